// Round 9
// baseline (668.476 us; speedup 1.0000x reference)
//
#include <hip/hip_runtime.h>
#include <hip/hip_bf16.h>

typedef __bf16 bf16;
typedef __bf16 v8bf __attribute__((ext_vector_type(8)));
typedef float f32x4 __attribute__((ext_vector_type(4)));
typedef float f32x2 __attribute__((ext_vector_type(2)));

#define NN 20000
#define EE 320000
#define FIN 256
#define D1 512
#define DOUT 128
#define ED 26

__device__ __forceinline__ float b2f(bf16 x) { return (float)x; }

__device__ __forceinline__ f32x2 ldbf2v(const bf16* p) {
  unsigned int u;
  __builtin_memcpy(&u, p, 4);
  union { unsigned int i; float f; } lo, hi;
  lo.i = (u & 0xffffu) << 16;
  hi.i = u & 0xffff0000u;
  return (f32x2){lo.f, hi.f};
}

__device__ __forceinline__ float ldbf1(const bf16* p) {
  unsigned short us;
  __builtin_memcpy(&us, p, 2);
  union { unsigned u; float f; } c;
  c.u = (unsigned)us << 16;
  return c.f;
}

__device__ __forceinline__ f32x2 ldf2v(const float* p) {
  f32x2 t;
  __builtin_memcpy(&t, p, 8);
  return t;
}

__device__ __forceinline__ f32x4 ldf4v(const float* p) {
  f32x4 t;
  __builtin_memcpy(&t, p, 16);
  return t;
}

// ---------------- small utils ----------------
__global__ void zero_k(int* __restrict__ p, int n) {
  int i = blockIdx.x * 256 + threadIdx.x;
  if (i < n) p[i] = 0;
}

// ---------------- edge_index dtype detect + convert ------------------------
__global__ void detflag_k(const int* __restrict__ ei32, int* __restrict__ flag) {
  int i = blockIdx.x * 256 + threadIdx.x;
  int v = (i < EE) ? ei32[2 * i + 1] : 0;
  unsigned long long b = __ballot(v != 0);
  if ((threadIdx.x & 63) == 0 && b) atomicOr(flag, 1);
}

__global__ void conv_k(const void* __restrict__ ei, const int* __restrict__ flag,
                       int* __restrict__ src, int* __restrict__ dst) {
  int i = blockIdx.x * 256 + threadIdx.x;
  if (i >= EE) return;
  int s, d;
  if (*flag == 0) {
    const long long* p = (const long long*)ei;
    s = (int)p[i];
    d = (int)p[EE + i];
  } else {
    const int* p = (const int*)ei;
    s = p[i];
    d = p[EE + i];
  }
  src[i] = min(max(s, 0), NN - 1);
  dst[i] = min(max(d, 0), NN - 1);
}

// ---------------- CSR build ----------------
__global__ void hist_k(const int* __restrict__ dst, int* __restrict__ deg, int n) {
  int e = blockIdx.x * 256 + threadIdx.x;
  if (e < n) atomicAdd(&deg[dst[e]], 1);
}

__global__ __launch_bounds__(1024) void scan_k(const int* __restrict__ deg,
                                               int* __restrict__ offs,
                                               int* __restrict__ cursor, int n) {
  __shared__ int lsum[1024];
  int t = threadIdx.x;
  const int CH = (n + 1023) / 1024;
  int base = t * CH;
  int s = 0;
  for (int i = 0; i < CH; i++) {
    int idx = base + i;
    if (idx < n) s += deg[idx];
  }
  lsum[t] = s;
  __syncthreads();
  for (int o = 1; o < 1024; o <<= 1) {
    int v = (t >= o) ? lsum[t - o] : 0;
    __syncthreads();
    lsum[t] += v;
    __syncthreads();
  }
  int ex = (t == 0) ? 0 : lsum[t - 1];
  for (int i = 0; i < CH; i++) {
    int idx = base + i;
    if (idx < n) {
      offs[idx] = ex;
      cursor[idx] = ex;
      ex += deg[idx];
    }
  }
  if (t == 1023) offs[n] = lsum[1023];
}

__global__ void scatter_k(const int* __restrict__ dst, int* __restrict__ cursor,
                          int* __restrict__ elist, int n) {
  int e = blockIdx.x * 256 + threadIdx.x;
  if (e < n) {
    int p = atomicAdd(&cursor[dst[e]], 1);
    if ((unsigned)p < (unsigned)EE) elist[p] = e;
  }
}

// ------- CSR-order gather of edge data: eatt rows (bf16, K-pad 32), src, dst
__global__ __launch_bounds__(256) void egather_k(
    const float* __restrict__ eatt, const int* __restrict__ elist,
    const int* __restrict__ srcs, const int* __restrict__ dsts,
    bf16* __restrict__ ea_csr, int* __restrict__ s_csr,
    int* __restrict__ d_csr) {
  __shared__ int e_s[128];
  int tid = threadIdx.x;
  int base = blockIdx.x * 128;  // EE = 2500 * 128
  if (tid < 128) {
    int e = elist[base + tid];
    e = min(max(e, 0), EE - 1);
    e_s[tid] = e;
    s_csr[base + tid] = srcs[e];
    d_csr[base + tid] = dsts[e];
  }
  __syncthreads();
  for (int idx = tid; idx < 128 * 32; idx += 256) {
    int i = idx >> 5, k = idx & 31;
    float v = (k < 26) ? eatt[(size_t)e_s[i] * ED + k] : 0.f;
    ea_csr[(size_t)(base + i) * 32 + k] = (bf16)v;
  }
}

// ------- x pre-pack: f32 -> bf16, same row-major layout --------------------
__global__ __launch_bounds__(256) void xpack_k(const float* __restrict__ x,
                                               bf16* __restrict__ xbf,
                                               long long n8) {
  long long i = (long long)blockIdx.x * 256 + threadIdx.x;
  if (i >= n8) return;
  const float* ap = x + i * 8;
  f32x4 u, v;
  __builtin_memcpy(&u, ap, 16);
  __builtin_memcpy(&v, ap + 4, 16);
  v8bf o;
#pragma unroll
  for (int j = 0; j < 4; j++) {
    o[j] = (bf16)u[j];
    o[4 + j] = (bf16)v[j];
  }
  __builtin_memcpy(xbf + i * 8, &o, 16);
}

// ------- weight pack: W [K][Nc] f32 -> Bp [Nc][K] bf16 (LDS tile transpose) -
__global__ __launch_bounds__(256) void packT_k(const float* __restrict__ W,
                                               bf16* __restrict__ Bp,
                                               int Nc, int K) {
  __shared__ float t[32][33];
  int c0 = blockIdx.x * 32, k0 = blockIdx.y * 32;
  int tr = threadIdx.x >> 5, tc = threadIdx.x & 31;
#pragma unroll
  for (int i = 0; i < 32; i += 8)
    t[tr + i][tc] = W[(size_t)(k0 + tr + i) * Nc + c0 + tc];
  __syncthreads();
#pragma unroll
  for (int i = 0; i < 32; i += 8)
    Bp[(size_t)(c0 + tr + i) * K + k0 + tc] = (bf16)t[tc][tr + i];
}

// ------- MFMA GEMM (single-output, for fallback skip ADD) ------------------
template <typename TA, typename TO, bool ADD>
__global__ __launch_bounds__(256) void gemm_t(const TA* __restrict__ A,
                                              const float* __restrict__ B,
                                              const float* __restrict__ bias,
                                              TO* out, int Nc, int K) {
  int w = threadIdx.x >> 6;
  int l = threadIdx.x & 63;
  int quad = l >> 4;
  int mrow = blockIdx.y * 16 + (l & 15);
  int col = blockIdx.x * 64 + w * 16 + (l & 15);
  f32x4 acc = {0.f, 0.f, 0.f, 0.f};
  for (int k0 = 0; k0 < K; k0 += 32) {
    int ka = k0 + quad * 8;
    v8bf a, b;
    if constexpr (sizeof(TA) == 4) {
      const float* ap = (const float*)A + (size_t)mrow * K + ka;
#pragma unroll
      for (int j = 0; j < 8; j++) a[j] = (bf16)ap[j];
    } else {
      __builtin_memcpy(&a, (const bf16*)A + (size_t)mrow * K + ka, 16);
    }
#pragma unroll
    for (int j = 0; j < 8; j++) b[j] = (bf16)B[(size_t)(ka + j) * Nc + col];
    acc = __builtin_amdgcn_mfma_f32_16x16x32_bf16(a, b, acc, 0, 0, 0);
  }
  float bb = bias[col];
  int obase = blockIdx.y * 16 + quad * 4;
#pragma unroll
  for (int r = 0; r < 4; r++) {
    size_t idx = (size_t)(obase + r) * Nc + col;
    float v = acc[r] + bb;
    if (ADD) v += (float)out[idx];
    out[idx] = (TO)v;
  }
}

// ------- 2-output fused MFMA GEMM (fallback path) --------------------------
template <typename TA, typename TO>
__global__ __launch_bounds__(256) void gemm2_t(const TA* __restrict__ A,
                                               const float* __restrict__ B0,
                                               const float* __restrict__ B1,
                                               const float* __restrict__ bias0,
                                               const float* __restrict__ bias1,
                                               TO* __restrict__ out0,
                                               TO* __restrict__ out1,
                                               int Nc, int K) {
  int w = threadIdx.x >> 6;
  int l = threadIdx.x & 63;
  int quad = l >> 4;
  int mrow = blockIdx.y * 16 + (l & 15);
  int col = blockIdx.x * 64 + w * 16 + (l & 15);
  f32x4 acc0 = {0.f, 0.f, 0.f, 0.f};
  f32x4 acc1 = {0.f, 0.f, 0.f, 0.f};
  for (int k0 = 0; k0 < K; k0 += 32) {
    int ka = k0 + quad * 8;
    v8bf a, b0, b1;
    if constexpr (sizeof(TA) == 4) {
      const float* ap = (const float*)A + (size_t)mrow * K + ka;
#pragma unroll
      for (int j = 0; j < 8; j++) a[j] = (bf16)ap[j];
    } else {
      __builtin_memcpy(&a, (const bf16*)A + (size_t)mrow * K + ka, 16);
    }
#pragma unroll
    for (int j = 0; j < 8; j++) {
      size_t bi = (size_t)(ka + j) * Nc + col;
      b0[j] = (bf16)B0[bi];
      b1[j] = (bf16)B1[bi];
    }
    acc0 = __builtin_amdgcn_mfma_f32_16x16x32_bf16(a, b0, acc0, 0, 0, 0);
    acc1 = __builtin_amdgcn_mfma_f32_16x16x32_bf16(a, b1, acc1, 0, 0, 0);
  }
  float bb0 = bias0[col], bb1 = bias1[col];
  int obase = blockIdx.y * 16 + quad * 4;
#pragma unroll
  for (int r = 0; r < 4; r++) {
    size_t idx = (size_t)(obase + r) * Nc + col;
    out0[idx] = (TO)(acc0[r] + bb0);
    out1[idx] = (TO)(acc1[r] + bb1);
  }
}

// ------- 3-output packed-B MFMA GEMM: 64x64 tile, 4 M-subtiles/wave --------
template <typename TA, typename TO>
__global__ __launch_bounds__(256) void gemm3p_t(
    const TA* __restrict__ A, const bf16* __restrict__ Bp,
    const float* __restrict__ bias0, const float* __restrict__ bias1,
    const float* __restrict__ bias2, TO* __restrict__ out0,
    TO* __restrict__ out1, TO* __restrict__ out2, int Nc, int K, int M) {
  int w = threadIdx.x >> 6;
  int l = threadIdx.x & 63;
  int quad = l >> 4, lc = l & 15;
  int col = blockIdx.x * 64 + w * 16 + lc;
  int mbase = blockIdx.y * 64;
  const bf16* b0p = Bp + (size_t)col * K;
  const bf16* b1p = Bp + ((size_t)Nc + col) * K;
  const bf16* b2p = Bp + ((size_t)2 * Nc + col) * K;
  f32x4 acc[4][3];
#pragma unroll
  for (int i = 0; i < 4; i++)
#pragma unroll
    for (int j = 0; j < 3; j++) acc[i][j] = (f32x4){0.f, 0.f, 0.f, 0.f};
  for (int k0 = 0; k0 < K; k0 += 32) {
    int ka = k0 + quad * 8;
    v8bf b0, b1, b2;
    __builtin_memcpy(&b0, b0p + ka, 16);
    __builtin_memcpy(&b1, b1p + ka, 16);
    __builtin_memcpy(&b2, b2p + ka, 16);
#pragma unroll
    for (int ms = 0; ms < 4; ms++) {
      int row = min(mbase + ms * 16 + lc, M - 1);
      v8bf a;
      if constexpr (sizeof(TA) == 4) {
        const float* ap = (const float*)A + (size_t)row * K + ka;
        f32x4 u, v;
        __builtin_memcpy(&u, ap, 16);
        __builtin_memcpy(&v, ap + 4, 16);
#pragma unroll
        for (int j = 0; j < 4; j++) {
          a[j] = (bf16)u[j];
          a[4 + j] = (bf16)v[j];
        }
      } else {
        __builtin_memcpy(&a, (const bf16*)A + (size_t)row * K + ka, 16);
      }
      acc[ms][0] = __builtin_amdgcn_mfma_f32_16x16x32_bf16(a, b0, acc[ms][0], 0, 0, 0);
      acc[ms][1] = __builtin_amdgcn_mfma_f32_16x16x32_bf16(a, b1, acc[ms][1], 0, 0, 0);
      acc[ms][2] = __builtin_amdgcn_mfma_f32_16x16x32_bf16(a, b2, acc[ms][2], 0, 0, 0);
    }
  }
  float bb0 = bias0[col], bb1 = bias1[col], bb2 = bias2[col];
#pragma unroll
  for (int ms = 0; ms < 4; ms++) {
    int ob = mbase + ms * 16 + quad * 4;
#pragma unroll
    for (int r = 0; r < 4; r++) {
      int orow = ob + r;
      if (orow < M) {
        size_t idx = (size_t)orow * Nc + col;
        out0[idx] = (TO)(acc[ms][0][r] + bb0);
        out1[idx] = (TO)(acc[ms][1][r] + bb1);
        out2[idx] = (TO)(acc[ms][2][r] + bb2);
      }
    }
  }
}

// ==== TIER-2: CSR-order MFMA alpha, ALL streaming reads contiguous =========
// Epilogue: r-outer / n-inner with hoisted row base pointers -> loads fold to
// immediate offsets (n*32 bytes); explicit u<<16 bf16->f32 converts.
__global__ __launch_bounds__(256) void alpha1c_k(
    const bf16* __restrict__ xl, const bf16* __restrict__ xr,
    const bf16* __restrict__ ea_csr, const float* __restrict__ We,
    const float* __restrict__ att, const int* __restrict__ s_csr,
    const int* __restrict__ d_csr, float* __restrict__ alphap) {
  __shared__ bf16 ea_s[128 * 40];
  int tid = threadIdx.x;
  int w = __builtin_amdgcn_readfirstlane(tid >> 6);
  int l = tid & 63;
  int quad = l >> 4, lc = l & 15;
  int base = blockIdx.x * 128;
  for (int idx = tid; idx < 1024; idx += 256) {
    int i = idx >> 3, k4 = (idx & 7) * 4;
    unsigned long long v;
    __builtin_memcpy(&v, ea_csr + (size_t)(base + i) * 32 + k4, 8);
    __builtin_memcpy(&ea_s[i * 40 + k4], &v, 8);
  }
  int c0 = w * 128;
  v8bf bfrag[8];
  float av[8];
#pragma unroll
  for (int n = 0; n < 8; n++) {
    int col = c0 + n * 16 + lc;
    av[n] = att[col];
#pragma unroll
    for (int j = 0; j < 8; j++) {
      int k = quad * 8 + j;
      bfrag[n][j] = (k < 26) ? (bf16)We[(size_t)k * D1 + col] : (bf16)0.f;
    }
  }
  __syncthreads();
#pragma unroll 1
  for (int m = 0; m < 8; m++) {
    v8bf afrag;
    __builtin_memcpy(&afrag, &ea_s[(m * 16 + lc) * 40 + quad * 8], 16);
    f32x4 z = {0.f, 0.f, 0.f, 0.f};
    f32x4 acc[8];
#pragma unroll
    for (int n = 0; n < 8; n++)
      acc[n] = __builtin_amdgcn_mfma_f32_16x16x32_bf16(afrag, bfrag[n], z, 0, 0, 0);
    int e0 = base + m * 16 + quad * 4;
    int sA[4], dA[4];
    __builtin_memcpy(sA, s_csr + e0, 16);
    __builtin_memcpy(dA, d_csr + e0, 16);
    f32x4 pal;
#pragma unroll
    for (int r = 0; r < 4; r++) {
      const bf16* xp = xl + (size_t)sA[r] * D1 + c0 + lc;
      const bf16* rp = xr + (size_t)dA[r] * D1 + c0 + lc;
      float p = 0.f;
#pragma unroll
      for (int n = 0; n < 8; n++) {
        float mm = ldbf1(xp + n * 16) + ldbf1(rp + n * 16) + acc[n][r];
        mm = fmaxf(mm, 0.f) + 0.2f * fminf(mm, 0.f);
        p += mm * av[n];
      }
      pal[r] = p;
    }
#pragma unroll
    for (int o = 1; o < 16; o <<= 1) {
      pal[0] += __shfl_xor(pal[0], o, 64);
      pal[1] += __shfl_xor(pal[1], o, 64);
      pal[2] += __shfl_xor(pal[2], o, 64);
      pal[3] += __shfl_xor(pal[3], o, 64);
    }
    if (lc == 0) {
#pragma unroll
      for (int r = 0; r < 4; r++) alphap[(size_t)(e0 + r) * 4 + w] = pal[r];
    }
  }
}

__global__ __launch_bounds__(256) void alpha2c_k(
    const float* __restrict__ xl, const float* __restrict__ xr,
    const bf16* __restrict__ ea_csr, const float* __restrict__ We,
    const float* __restrict__ att, const int* __restrict__ s_csr,
    const int* __restrict__ d_csr, float* __restrict__ alphap) {
  __shared__ bf16 ea_s[128 * 40];
  __shared__ float pal_s[4 * 128];
  int tid = threadIdx.x;
  int w = __builtin_amdgcn_readfirstlane(tid >> 6);
  int l = tid & 63;
  int quad = l >> 4, lc = l & 15;
  int base = blockIdx.x * 128;
  for (int idx = tid; idx < 1024; idx += 256) {
    int i = idx >> 3, k4 = (idx & 7) * 4;
    unsigned long long v;
    __builtin_memcpy(&v, ea_csr + (size_t)(base + i) * 32 + k4, 8);
    __builtin_memcpy(&ea_s[i * 40 + k4], &v, 8);
  }
  int c0 = w * 32;
  v8bf bfrag[2];
  float av[2];
#pragma unroll
  for (int n = 0; n < 2; n++) {
    int col = c0 + n * 16 + lc;
    av[n] = att[col];
#pragma unroll
    for (int j = 0; j < 8; j++) {
      int k = quad * 8 + j;
      bfrag[n][j] = (k < 26) ? (bf16)We[(size_t)k * DOUT + col] : (bf16)0.f;
    }
  }
  __syncthreads();
#pragma unroll 1
  for (int m = 0; m < 8; m++) {
    v8bf afrag;
    __builtin_memcpy(&afrag, &ea_s[(m * 16 + lc) * 40 + quad * 8], 16);
    f32x4 z = {0.f, 0.f, 0.f, 0.f};
    f32x4 acc[2];
#pragma unroll
    for (int n = 0; n < 2; n++)
      acc[n] = __builtin_amdgcn_mfma_f32_16x16x32_bf16(afrag, bfrag[n], z, 0, 0, 0);
    int e0 = base + m * 16 + quad * 4;
    int sA[4], dA[4];
    __builtin_memcpy(sA, s_csr + e0, 16);
    __builtin_memcpy(dA, d_csr + e0, 16);
    f32x4 pal;
#pragma unroll
    for (int r = 0; r < 4; r++) {
      const float* xp = xl + (size_t)sA[r] * DOUT + c0 + lc;
      const float* rp = xr + (size_t)dA[r] * DOUT + c0 + lc;
      float p = 0.f;
#pragma unroll
      for (int n = 0; n < 2; n++) {
        float mm = xp[n * 16] + rp[n * 16] + acc[n][r];
        mm = fmaxf(mm, 0.f) + 0.2f * fminf(mm, 0.f);
        p += mm * av[n];
      }
      pal[r] = p;
    }
#pragma unroll
    for (int o = 1; o < 16; o <<= 1) {
      pal[0] += __shfl_xor(pal[0], o, 64);
      pal[1] += __shfl_xor(pal[1], o, 64);
      pal[2] += __shfl_xor(pal[2], o, 64);
      pal[3] += __shfl_xor(pal[3], o, 64);
    }
    if (lc == 0) {
      int eb = m * 16 + quad * 4;
#pragma unroll
      for (int r = 0; r < 4; r++) pal_s[w * 128 + eb + r] = pal[r];
    }
  }
  __syncthreads();
  if (tid < 128) {
    float a = pal_s[tid] + pal_s[128 + tid] + pal_s[256 + tid] + pal_s[384 + tid];
    alphap[base + tid] = a;
  }
}

// ==== TIER-2 aggs: wave-per-node, contiguous alpha/s reads, lane-par max ===
__global__ __launch_bounds__(256) void agg1c_k(
    const bf16* __restrict__ xl, const bf16* __restrict__ skip,
    const float* __restrict__ alphap, const float* __restrict__ bias,
    const float* __restrict__ g, const float* __restrict__ be,
    const int* __restrict__ s_csr, const int* __restrict__ offs,
    bf16* __restrict__ hout) {
  int tid = threadIdx.x;
  int w = tid >> 6, l = tid & 63;
  int node = blockIdx.x * 4 + w;
  if (node >= NN) return;
  int c = l * 8;
  int head = l >> 4;
  int i0 = offs[node], i1 = offs[node + 1];
  i0 = max(0, min(i0, EE));
  i1 = max(i0, min(i1, EE));
  float m = -3.0e38f;
  for (int i = i0 + (l & 15); i < i1; i += 16)
    m = fmaxf(m, alphap[(size_t)i * 4 + head]);
#pragma unroll
  for (int o = 1; o < 16; o <<= 1) m = fmaxf(m, __shfl_xor(m, o, 64));
  float den = 0.f;
  f32x4 a0 = {0.f, 0.f, 0.f, 0.f}, a1 = {0.f, 0.f, 0.f, 0.f};
  int s = 0;
  float al = 0.f;
  if (i0 < i1) {
    s = __builtin_amdgcn_readfirstlane(s_csr[i0]);
    al = alphap[(size_t)i0 * 4 + head];
  }
  for (int i = i0; i < i1; i++) {
    int s_n = s;
    float al_n = al;
    if (i + 1 < i1) {
      s_n = __builtin_amdgcn_readfirstlane(s_csr[i + 1]);
      al_n = alphap[(size_t)(i + 1) * 4 + head];
    }
    float pr = __expf(al - m);
    den += pr;
    v8bf xv;
    __builtin_memcpy(&xv, xl + (size_t)s * D1 + c, 16);
#pragma unroll
    for (int j = 0; j < 4; j++) {
      a0[j] += pr * (float)xv[j];
      a1[j] += pr * (float)xv[4 + j];
    }
    s = s_n;
    al = al_n;
  }
  float inv = 1.f / (den + 1e-16f);
  v8bf skv;
  __builtin_memcpy(&skv, skip + (size_t)node * D1 + c, 16);
  f32x4 bv0 = ldf4v(bias + c), bv1 = ldf4v(bias + c + 4);
  float o[8];
#pragma unroll
  for (int j = 0; j < 4; j++) {
    o[j] = a0[j] * inv + bv0[j] + (float)skv[j];
    o[4 + j] = a1[j] * inv + bv1[j] + (float)skv[4 + j];
  }
  float s1 = 0.f, s2 = 0.f;
#pragma unroll
  for (int j = 0; j < 8; j++) {
    s1 += o[j];
    s2 += o[j] * o[j];
  }
#pragma unroll
  for (int of = 32; of; of >>= 1) {
    s1 += __shfl_xor(s1, of, 64);
    s2 += __shfl_xor(s2, of, 64);
  }
  float mu = s1 * (1.f / 512.f);
  float var = fmaxf(s2 * (1.f / 512.f) - mu * mu, 0.f);
  float rs = rsqrtf(var + 1e-5f);
  f32x4 gv0 = ldf4v(g + c), gv1 = ldf4v(g + c + 4);
  f32x4 ev0 = ldf4v(be + c), ev1 = ldf4v(be + c + 4);
  v8bf hv;
#pragma unroll
  for (int j = 0; j < 4; j++) {
    float y0 = (o[j] - mu) * rs * gv0[j] + ev0[j];
    float y1 = (o[4 + j] - mu) * rs * gv1[j] + ev1[j];
    y0 = y0 > 0.f ? y0 : __expf(fminf(y0, 0.f)) - 1.f;
    y1 = y1 > 0.f ? y1 : __expf(fminf(y1, 0.f)) - 1.f;
    hv[j] = (bf16)y0;
    hv[4 + j] = (bf16)y1;
  }
  __builtin_memcpy(hout + (size_t)node * D1 + c, &hv, 16);
}

__global__ __launch_bounds__(256) void agg2c_k(
    const float* __restrict__ xl, const float* __restrict__ skip,
    const float* __restrict__ alphap, const float* __restrict__ bias,
    const float* __restrict__ g, const float* __restrict__ be,
    const int* __restrict__ s_csr, const int* __restrict__ offs,
    float* __restrict__ outp) {
  int tid = threadIdx.x;
  int w = tid >> 6, l = tid & 63;
  int node = blockIdx.x * 4 + w;
  if (node >= NN) return;
  int c = 2 * l;
  int i0 = offs[node], i1 = offs[node + 1];
  i0 = max(0, min(i0, EE));
  i1 = max(i0, min(i1, EE));
  float m = -3.0e38f;
  for (int i = i0 + l; i < i1; i += 64) m = fmaxf(m, alphap[i]);
#pragma unroll
  for (int o = 32; o; o >>= 1) m = fmaxf(m, __shfl_xor(m, o, 64));
  float den = 0.f;
  f32x2 acc = {0.f, 0.f};
  int s = 0;
  float al = 0.f;
  if (i0 < i1) {
    s = __builtin_amdgcn_readfirstlane(s_csr[i0]);
    al = alphap[i0];
  }
  for (int i = i0; i < i1; i++) {
    int s_n = s;
    float al_n = al;
    if (i + 1 < i1) {
      s_n = __builtin_amdgcn_readfirstlane(s_csr[i + 1]);
      al_n = alphap[i + 1];
    }
    float pr = __expf(al - m);
    den += pr;
    f32x2 xv = ldf2v(xl + (size_t)s * DOUT + c);
    acc += (f32x2){pr, pr} * xv;
    s = s_n;
    al = al_n;
  }
  float inv = 1.f / (den + 1e-16f);
  f32x2 sk = ldf2v(skip + (size_t)node * DOUT + c);
  float o0 = acc.x * inv + bias[c] + sk.x;
  float o1 = acc.y * inv + bias[c + 1] + sk.y;
  float s1 = o0 + o1, s2 = o0 * o0 + o1 * o1;
#pragma unroll
  for (int of = 32; of; of >>= 1) {
    s1 += __shfl_xor(s1, of, 64);
    s2 += __shfl_xor(s2, of, 64);
  }
  float mu = s1 * (1.f / 128.f);
  float var = fmaxf(s2 * (1.f / 128.f) - mu * mu, 0.f);
  float rs = rsqrtf(var + 1e-5f);
  outp[(size_t)node * DOUT + c] = (o0 - mu) * rs * g[c] + be[c];
  outp[(size_t)node * DOUT + c + 1] = (o1 - mu) * rs * g[c + 1] + be[c + 1];
}

// ==== TIER-1 (R6) kernels: edge-order alpha + elist-indirect aggs ==========
__global__ __launch_bounds__(256) void alpha1_k(
    const bf16* __restrict__ xl, const bf16* __restrict__ xr,
    const float* __restrict__ eatt, const float* __restrict__ We,
    const float* __restrict__ att, const int* __restrict__ srcs,
    const int* __restrict__ dsts, float* __restrict__ alpha) {
  __shared__ bf16 ea_s[128 * 40];
  int tid = threadIdx.x;
  int w = __builtin_amdgcn_readfirstlane(tid >> 6);
  int l = tid & 63;
  int quad = l >> 4, lc = l & 15;
  int base = blockIdx.x * 128;
  for (int i = tid; i < 128 * 32; i += 256) {
    int e = i >> 5, k = i & 31;
    float v = (k < 26) ? eatt[(size_t)(base + e) * ED + k] : 0.f;
    ea_s[e * 40 + k] = (bf16)v;
  }
  int c0 = w * 128;
  v8bf bfrag[8];
  float av[8];
#pragma unroll
  for (int n = 0; n < 8; n++) {
    int col = c0 + n * 16 + lc;
    av[n] = att[col];
#pragma unroll
    for (int j = 0; j < 8; j++) {
      int k = quad * 8 + j;
      bfrag[n][j] = (k < 26) ? (bf16)We[(size_t)k * D1 + col] : (bf16)0.f;
    }
  }
  __syncthreads();
#pragma unroll 1
  for (int m = 0; m < 8; m++) {
    v8bf afrag;
    __builtin_memcpy(&afrag, &ea_s[(m * 16 + lc) * 40 + quad * 8], 16);
    f32x4 z = {0.f, 0.f, 0.f, 0.f};
    f32x4 acc[8];
#pragma unroll
    for (int n = 0; n < 8; n++)
      acc[n] = __builtin_amdgcn_mfma_f32_16x16x32_bf16(afrag, bfrag[n], z, 0, 0, 0);
    int e0 = base + m * 16 + quad * 4;
    int sA[4], dA[4];
#pragma unroll
    for (int r = 0; r < 4; r++) {
      sA[r] = srcs[e0 + r];
      dA[r] = dsts[e0 + r];
    }
    f32x4 pal = {0.f, 0.f, 0.f, 0.f};
#pragma unroll
    for (int n = 0; n < 8; n++) {
      int col = c0 + n * 16 + lc;
#pragma unroll
      for (int r = 0; r < 4; r++) {
        float mm = (float)xl[(size_t)sA[r] * D1 + col] +
                   (float)xr[(size_t)dA[r] * D1 + col] + acc[n][r];
        mm = fmaxf(mm, 0.f) + 0.2f * fminf(mm, 0.f);
        pal[r] += mm * av[n];
      }
    }
#pragma unroll
    for (int o = 1; o < 16; o <<= 1) {
      pal[0] += __shfl_xor(pal[0], o, 64);
      pal[1] += __shfl_xor(pal[1], o, 64);
      pal[2] += __shfl_xor(pal[2], o, 64);
      pal[3] += __shfl_xor(pal[3], o, 64);
    }
    if (lc == 0) {
#pragma unroll
      for (int r = 0; r < 4; r++) alpha[(size_t)(e0 + r) * 4 + w] = pal[r];
    }
  }
}

__global__ __launch_bounds__(256) void alpha2_k(
    const float* __restrict__ xl, const float* __restrict__ xr,
    const float* __restrict__ eatt, const float* __restrict__ We,
    const float* __restrict__ att, const int* __restrict__ srcs,
    const int* __restrict__ dsts, float* __restrict__ alpha) {
  __shared__ bf16 ea_s[128 * 40];
  __shared__ float pal_s[4 * 128];
  int tid = threadIdx.x;
  int w = __builtin_amdgcn_readfirstlane(tid >> 6);
  int l = tid & 63;
  int quad = l >> 4, lc = l & 15;
  int base = blockIdx.x * 128;
  for (int i = tid; i < 128 * 32; i += 256) {
    int e = i >> 5, k = i & 31;
    float v = (k < 26) ? eatt[(size_t)(base + e) * ED + k] : 0.f;
    ea_s[e * 40 + k] = (bf16)v;
  }
  int c0 = w * 32;
  v8bf bfrag[2];
  float av[2];
#pragma unroll
  for (int n = 0; n < 2; n++) {
    int col = c0 + n * 16 + lc;
    av[n] = att[col];
#pragma unroll
    for (int j = 0; j < 8; j++) {
      int k = quad * 8 + j;
      bfrag[n][j] = (k < 26) ? (bf16)We[(size_t)k * DOUT + col] : (bf16)0.f;
    }
  }
  __syncthreads();
#pragma unroll 1
  for (int m = 0; m < 8; m++) {
    v8bf afrag;
    __builtin_memcpy(&afrag, &ea_s[(m * 16 + lc) * 40 + quad * 8], 16);
    f32x4 z = {0.f, 0.f, 0.f, 0.f};
    f32x4 acc[2];
#pragma unroll
    for (int n = 0; n < 2; n++)
      acc[n] = __builtin_amdgcn_mfma_f32_16x16x32_bf16(afrag, bfrag[n], z, 0, 0, 0);
    int e0 = base + m * 16 + quad * 4;
    int sA[4], dA[4];
#pragma unroll
    for (int r = 0; r < 4; r++) {
      sA[r] = srcs[e0 + r];
      dA[r] = dsts[e0 + r];
    }
    f32x4 pal = {0.f, 0.f, 0.f, 0.f};
#pragma unroll
    for (int n = 0; n < 2; n++) {
      int col = c0 + n * 16 + lc;
#pragma unroll
      for (int r = 0; r < 4; r++) {
        float mm = xl[(size_t)sA[r] * DOUT + col] +
                   xr[(size_t)dA[r] * DOUT + col] + acc[n][r];
        mm = fmaxf(mm, 0.f) + 0.2f * fminf(mm, 0.f);
        pal[r] += mm * av[n];
      }
    }
#pragma unroll
    for (int o = 1; o < 16; o <<= 1) {
      pal[0] += __shfl_xor(pal[0], o, 64);
      pal[1] += __shfl_xor(pal[1], o, 64);
      pal[2] += __shfl_xor(pal[2], o, 64);
      pal[3] += __shfl_xor(pal[3], o, 64);
    }
    if (lc == 0) {
      int eb = m * 16 + quad * 4;
#pragma unroll
      for (int r = 0; r < 4; r++) pal_s[w * 128 + eb + r] = pal[r];
    }
  }
  __syncthreads();
  if (tid < 128) {
    float a = pal_s[tid] + pal_s[128 + tid] + pal_s[256 + tid] + pal_s[384 + tid];
    alpha[base + tid] = a;
  }
}

__global__ __launch_bounds__(256) void agg1_k(
    const bf16* __restrict__ xl, const bf16* __restrict__ skip,
    const float* __restrict__ alpha, const float* __restrict__ bias,
    const float* __restrict__ g, const float* __restrict__ be,
    const int* __restrict__ srcs, const int* __restrict__ offs,
    const int* __restrict__ elist, bf16* __restrict__ hout) {
  int tid = threadIdx.x;
  int w = tid >> 6, l = tid & 63;
  int node = blockIdx.x * 4 + w;
  if (node >= NN) return;
  int c = l * 8;
  int head = l >> 4;
  int i0 = offs[node], i1 = offs[node + 1];
  i0 = max(0, min(i0, EE));
  i1 = max(i0, min(i1, EE));
  float m = -3.0e38f;
  for (int i = i0; i < i1; i++) {
    int e = __builtin_amdgcn_readfirstlane(elist[i]);
    m = fmaxf(m, alpha[(size_t)e * 4 + head]);
  }
  float den = 0.f;
  f32x4 a0 = {0.f, 0.f, 0.f, 0.f}, a1 = {0.f, 0.f, 0.f, 0.f};
  int s = 0;
  float al = 0.f;
  if (i0 < i1) {
    int e = __builtin_amdgcn_readfirstlane(elist[i0]);
    s = __builtin_amdgcn_readfirstlane(srcs[e]);
    al = alpha[(size_t)e * 4 + head];
  }
  for (int i = i0; i < i1; i++) {
    int s_n = s;
    float al_n = al;
    if (i + 1 < i1) {
      int e = __builtin_amdgcn_readfirstlane(elist[i + 1]);
      s_n = __builtin_amdgcn_readfirstlane(srcs[e]);
      al_n = alpha[(size_t)e * 4 + head];
    }
    float pr = __expf(al - m);
    den += pr;
    v8bf xv;
    __builtin_memcpy(&xv, xl + (size_t)s * D1 + c, 16);
#pragma unroll
    for (int j = 0; j < 4; j++) {
      a0[j] += pr * (float)xv[j];
      a1[j] += pr * (float)xv[4 + j];
    }
    s = s_n;
    al = al_n;
  }
  float inv = 1.f / (den + 1e-16f);
  v8bf skv;
  __builtin_memcpy(&skv, skip + (size_t)node * D1 + c, 16);
  f32x4 bv0 = ldf4v(bias + c), bv1 = ldf4v(bias + c + 4);
  float o[8];
#pragma unroll
  for (int j = 0; j < 4; j++) {
    o[j] = a0[j] * inv + bv0[j] + (float)skv[j];
    o[4 + j] = a1[j] * inv + bv1[j] + (float)skv[4 + j];
  }
  float s1 = 0.f, s2 = 0.f;
#pragma unroll
  for (int j = 0; j < 8; j++) {
    s1 += o[j];
    s2 += o[j] * o[j];
  }
#pragma unroll
  for (int of = 32; of; of >>= 1) {
    s1 += __shfl_xor(s1, of, 64);
    s2 += __shfl_xor(s2, of, 64);
  }
  float mu = s1 * (1.f / 512.f);
  float var = fmaxf(s2 * (1.f / 512.f) - mu * mu, 0.f);
  float rs = rsqrtf(var + 1e-5f);
  f32x4 gv0 = ldf4v(g + c), gv1 = ldf4v(g + c + 4);
  f32x4 ev0 = ldf4v(be + c), ev1 = ldf4v(be + c + 4);
  v8bf hv;
#pragma unroll
  for (int j = 0; j < 4; j++) {
    float y0 = (o[j] - mu) * rs * gv0[j] + ev0[j];
    float y1 = (o[4 + j] - mu) * rs * gv1[j] + ev1[j];
    y0 = y0 > 0.f ? y0 : __expf(fminf(y0, 0.f)) - 1.f;
    y1 = y1 > 0.f ? y1 : __expf(fminf(y1, 0.f)) - 1.f;
    hv[j] = (bf16)y0;
    hv[4 + j] = (bf16)y1;
  }
  __builtin_memcpy(hout + (size_t)node * D1 + c, &hv, 16);
}

__global__ __launch_bounds__(256) void agg2_k(
    const float* __restrict__ xl, const float* __restrict__ skip,
    const float* __restrict__ alpha, const float* __restrict__ bias,
    const float* __restrict__ g, const float* __restrict__ be,
    const int* __restrict__ srcs, const int* __restrict__ offs,
    const int* __restrict__ elist, float* __restrict__ outp) {
  int tid = threadIdx.x;
  int w = tid >> 6, l = tid & 63;
  int node = blockIdx.x * 4 + w;
  if (node >= NN) return;
  int c = 2 * l;
  int i0 = offs[node], i1 = offs[node + 1];
  i0 = max(0, min(i0, EE));
  i1 = max(i0, min(i1, EE));
  float m = -3.0e38f;
  for (int i = i0; i < i1; i++) {
    int e = __builtin_amdgcn_readfirstlane(elist[i]);
    m = fmaxf(m, alpha[e]);
  }
  float den = 0.f;
  f32x2 acc = {0.f, 0.f};
  int s = 0;
  float al = 0.f;
  if (i0 < i1) {
    int e = __builtin_amdgcn_readfirstlane(elist[i0]);
    s = __builtin_amdgcn_readfirstlane(srcs[e]);
    al = alpha[e];
  }
  for (int i = i0; i < i1; i++) {
    int s_n = s;
    float al_n = al;
    if (i + 1 < i1) {
      int e = __builtin_amdgcn_readfirstlane(elist[i + 1]);
      s_n = __builtin_amdgcn_readfirstlane(srcs[e]);
      al_n = alpha[e];
    }
    float pr = __expf(al - m);
    den += pr;
    f32x2 xv = ldf2v(xl + (size_t)s * DOUT + c);
    acc += (f32x2){pr, pr} * xv;
    s = s_n;
    al = al_n;
  }
  float inv = 1.f / (den + 1e-16f);
  f32x2 sk = ldf2v(skip + (size_t)node * DOUT + c);
  float o0 = acc.x * inv + bias[c] + sk.x;
  float o1 = acc.y * inv + bias[c + 1] + sk.y;
  float s1 = o0 + o1, s2 = o0 * o0 + o1 * o1;
#pragma unroll
  for (int of = 32; of; of >>= 1) {
    s1 += __shfl_xor(s1, of, 64);
    s2 += __shfl_xor(s2, of, 64);
  }
  float mu = s1 * (1.f / 128.f);
  float var = fmaxf(s2 * (1.f / 128.f) - mu * mu, 0.f);
  float rs = rsqrtf(var + 1e-5f);
  outp[(size_t)node * DOUT + c] = (o0 - mu) * rs * g[c] + be[c];
  outp[(size_t)node * DOUT + c + 1] = (o1 - mu) * rs * g[c + 1] + be[c + 1];
}

// ---------------- fallback kernels (r12): agg w/o LN, lnelu, ln128 ---------
__global__ __launch_bounds__(256) void l1_agg(
    const bf16* __restrict__ xl, const bf16* xr,
    const float* __restrict__ eatt, const float* __restrict__ We,
    const float* __restrict__ att, const float* __restrict__ bias,
    const int* __restrict__ srcs, const int* __restrict__ offs,
    const int* __restrict__ elist, bf16* hout) {
  int node = blockIdx.x;
  int tid = threadIdx.x;
  int w = tid >> 6, l = tid & 63;
  int c = w * 128 + 2 * l;
  f32x2 we[ED];
#pragma unroll
  for (int j = 0; j < ED; j++) {
    we[j] = (f32x2){We[(size_t)j * D1 + c], We[(size_t)j * D1 + c + 1]};
  }
  f32x2 av = ldf2v(att + c);
  f32x2 rv = ldbf2v(xr + (size_t)node * D1 + c);
  float m = -3.0e38f, den = 0.f;
  f32x2 acc = {0.f, 0.f};
  int i0 = offs[node], i1 = offs[node + 1];
  i0 = max(0, min(i0, EE));
  i1 = max(i0, min(i1, EE));
  int e = 0, s = 0;
  if (i0 < i1) {
    e = __builtin_amdgcn_readfirstlane(elist[i0]);
    s = __builtin_amdgcn_readfirstlane(srcs[e]);
  }
  for (int i = i0; i < i1; i++) {
    int e_n = e, s_n = s;
    if (i + 1 < i1) {
      e_n = __builtin_amdgcn_readfirstlane(elist[i + 1]);
      s_n = __builtin_amdgcn_readfirstlane(srcs[e_n]);
    }
    f32x2 xv = ldbf2v(xl + (size_t)s * D1 + c);
    const float* ear = eatt + (size_t)e * ED;
    f32x2 et = {0.f, 0.f};
#pragma unroll
    for (int j = 0; j < ED; j += 2) {
      f32x2 t = ldf2v(ear + j);
      et += (f32x2){t.x, t.x} * we[j];
      et += (f32x2){t.y, t.y} * we[j + 1];
    }
    f32x2 mm = xv + rv + et;
    f32x2 pos = {fmaxf(mm.x, 0.f), fmaxf(mm.y, 0.f)};
    f32x2 neg = {fminf(mm.x, 0.f), fminf(mm.y, 0.f)};
    mm = pos + 0.2f * neg;
    float al = mm.x * av.x + mm.y * av.y;
#pragma unroll
    for (int o = 32; o; o >>= 1) al += __shfl_xor(al, o, 64);
    float nm = fmaxf(m, al);
    float sc = __expf(m - nm);
    float pr = __expf(al - nm);
    den = den * sc + pr;
    acc = acc * sc + (f32x2){pr, pr} * xv;
    m = nm;
    e = e_n;
    s = s_n;
  }
  float inv = 1.f / (den + 1e-16f);
  hout[(size_t)node * D1 + c] = (bf16)(acc.x * inv + bias[c]);
  hout[(size_t)node * D1 + c + 1] = (bf16)(acc.y * inv + bias[c + 1]);
}

__global__ __launch_bounds__(256) void l2_agg(
    const float* __restrict__ xl, const float* xr,
    const float* __restrict__ eatt, const float* __restrict__ We,
    const float* __restrict__ att, const float* __restrict__ bias,
    const int* __restrict__ srcs, const int* __restrict__ offs,
    const int* __restrict__ elist, float* hout) {
  int tid = threadIdx.x;
  int w = tid >> 6, l = tid & 63;
  int node = blockIdx.x * 4 + w;
  if (node >= NN) return;
  int c = 2 * l;
  f32x2 we[ED];
#pragma unroll
  for (int j = 0; j < ED; j++) {
    we[j] = (f32x2){We[(size_t)j * DOUT + c], We[(size_t)j * DOUT + c + 1]};
  }
  f32x2 av = ldf2v(att + c);
  f32x2 rv = ldf2v(xr + (size_t)node * DOUT + c);
  float m = -3.0e38f, den = 0.f;
  f32x2 acc = {0.f, 0.f};
  int i0 = offs[node], i1 = offs[node + 1];
  i0 = max(0, min(i0, EE));
  i1 = max(i0, min(i1, EE));
  int e = 0, s = 0;
  if (i0 < i1) {
    e = __builtin_amdgcn_readfirstlane(elist[i0]);
    s = __builtin_amdgcn_readfirstlane(srcs[e]);
  }
  for (int i = i0; i < i1; i++) {
    int e_n = e, s_n = s;
    if (i + 1 < i1) {
      e_n = __builtin_amdgcn_readfirstlane(elist[i + 1]);
      s_n = __builtin_amdgcn_readfirstlane(srcs[e_n]);
    }
    f32x2 xv = ldf2v(xl + (size_t)s * DOUT + c);
    const float* ear = eatt + (size_t)e * ED;
    f32x2 et = {0.f, 0.f};
#pragma unroll
    for (int j = 0; j < ED; j += 2) {
      f32x2 t = ldf2v(ear + j);
      et += (f32x2){t.x, t.x} * we[j];
      et += (f32x2){t.y, t.y} * we[j + 1];
    }
    f32x2 mm = xv + rv + et;
    f32x2 pos = {fmaxf(mm.x, 0.f), fmaxf(mm.y, 0.f)};
    f32x2 neg = {fminf(mm.x, 0.f), fminf(mm.y, 0.f)};
    mm = pos + 0.2f * neg;
    float al = mm.x * av.x + mm.y * av.y;
#pragma unroll
    for (int o = 32; o; o >>= 1) al += __shfl_xor(al, o, 64);
    float nm = fmaxf(m, al);
    float sc = __expf(m - nm);
    float pr = __expf(al - nm);
    den = den * sc + pr;
    acc = acc * sc + (f32x2){pr, pr} * xv;
    m = nm;
    e = e_n;
    s = s_n;
  }
  float inv = 1.f / (den + 1e-16f);
  hout[(size_t)node * DOUT + c] = acc.x * inv + bias[c];
  hout[(size_t)node * DOUT + c + 1] = acc.y * inv + bias[c + 1];
}

__global__ __launch_bounds__(256) void lnelu_k(bf16* buf,
                                               const float* __restrict__ g,
                                               const float* __restrict__ be) {
  int node = blockIdx.x, tid = threadIdx.x;
  int w = tid >> 6, l = tid & 63;
  int c = tid * 2;
  f32x2 o = ldbf2v(buf + (size_t)node * D1 + c);
  float s1 = o.x + o.y, s2 = o.x * o.x + o.y * o.y;
#pragma unroll
  for (int of = 32; of; of >>= 1) {
    s1 += __shfl_xor(s1, of, 64);
    s2 += __shfl_xor(s2, of, 64);
  }
  __shared__ float r1[4], r2[4];
  if (l == 0) { r1[w] = s1; r2[w] = s2; }
  __syncthreads();
  float S1 = r1[0] + r1[1] + r1[2] + r1[3];
  float S2 = r2[0] + r2[1] + r2[2] + r2[3];
  float mu = S1 * (1.f / 512.f);
  float var = fmaxf(S2 * (1.f / 512.f) - mu * mu, 0.f);
  float rs = rsqrtf(var + 1e-5f);
  float y0 = (o.x - mu) * rs * g[c] + be[c];
  float y1 = (o.y - mu) * rs * g[c + 1] + be[c + 1];
  y0 = y0 > 0.f ? y0 : __expf(fminf(y0, 0.f)) - 1.f;
  y1 = y1 > 0.f ? y1 : __expf(fminf(y1, 0.f)) - 1.f;
  buf[(size_t)node * D1 + c] = (bf16)y0;
  buf[(size_t)node * D1 + c + 1] = (bf16)y1;
}

__global__ __launch_bounds__(256) void ln128_k(const float* __restrict__ buf,
                                               const float* __restrict__ g,
                                               const float* __restrict__ be,
                                               float* __restrict__ outp) {
  int tid = threadIdx.x;
  int w = tid >> 6, l = tid & 63;
  int node = blockIdx.x * 4 + w;
  if (node >= NN) return;
  int c = 2 * l;
  f32x2 o = ldf2v(buf + (size_t)node * DOUT + c);
  float s1 = o.x + o.y, s2 = o.x * o.x + o.y * o.y;
#pragma unroll
  for (int of = 32; of; of >>= 1) {
    s1 += __shfl_xor(s1, of, 64);
    s2 += __shfl_xor(s2, of, 64);
  }
  float mu = s1 * (1.f / 128.f);
  float var = fmaxf(s2 * (1.f / 128.f) - mu * mu, 0.f);
  float rs = rsqrtf(var + 1e-5f);
  outp[(size_t)node * DOUT + c] = (o.x - mu) * rs * g[c] + be[c];
  outp[(size_t)node * DOUT + c + 1] = (o.y - mu) * rs * g[c + 1] + be[c + 1];
}

extern "C" void kernel_launch(void* const* d_in, const int* in_sizes, int n_in,
                              void* d_out, int out_size, void* d_ws, size_t ws_size,
                              hipStream_t stream) {
  const float* x = (const float*)d_in[0];
  const void* ei = d_in[1];
  const float* eattr = (const float*)d_in[2];
  const float* W1l = (const float*)d_in[3];
  const float* b1l = (const float*)d_in[4];
  const float* W1r = (const float*)d_in[5];
  const float* b1r = (const float*)d_in[6];
  const float* We1 = (const float*)d_in[7];
  const float* att1 = (const float*)d_in[8];
  const float* bias1 = (const float*)d_in[9];
  const float* Wsk1 = (const float*)d_in[10];
  const float* bsk1 = (const float*)d_in[11];
  const float* g1 = (const float*)d_in[12];
  const float* be1 = (const float*)d_in[13];
  const float* W2l = (const float*)d_in[14];
  const float* b2l = (const float*)d_in[15];
  const float* W2r = (const float*)d_in[16];
  const float* b2r = (const float*)d_in[17];
  const float* We2 = (const float*)d_in[18];
  const float* att2 = (const float*)d_in[19];
  const float* bias2 = (const float*)d_in[20];
  const float* Wsk2 = (const float*)d_in[21];
  const float* bsk2 = (const float*)d_in[22];
  const float* g2 = (const float*)d_in[23];
  const float* be2 = (const float*)d_in[24];

  // workspace carve (256B aligned)
  char* p = (char*)d_ws;
  size_t off = 0;
  auto carve = [&](size_t bytes) {
    void* r = p + off;
    off = (off + bytes + 255) & ~(size_t)255;
    return r;
  };
  int* flag = (int*)carve(sizeof(int));
  int* srcD = (int*)carve(EE * sizeof(int));
  int* dstD = (int*)carve(EE * sizeof(int));
  int* deg = (int*)carve(NN * sizeof(int));
  int* offs = (int*)carve((NN + 1) * sizeof(int));
  int* cursor = (int*)carve(NN * sizeof(int));
  int* elist = (int*)carve(EE * sizeof(int));
  bf16* bufA = (bf16*)carve((size_t)NN * D1 * 2);  // xl1; then f32 x2l/x2r
  bf16* bufB = (bf16*)carve((size_t)NN * D1 * 2);  // xr1 -> h -> alpha2 scratch
  size_t base_need = off;
  bf16* bufC = (bf16*)carve((size_t)NN * D1 * 2);  // skip1 bf16 / skip2 f32
  bool fused = (off <= ws_size);
  // tier-2 extras: CSR-gathered edge data
  bf16* eacsr = (bf16*)carve((size_t)EE * 32 * 2);  // [E][32] bf16, K-pad 0
  int* s_csr = (int*)carve(EE * sizeof(int));
  int* d_csr = (int*)carve(EE * sizeof(int));
  bool fused2 = (off <= ws_size);
  // tier-3: x pre-packed to bf16 (layer-1 GEMM A fast path)
  bf16* xbf = (bf16*)carve((size_t)NN * FIN * 2);
  bool fused3 = (off <= ws_size);

  float* q0 = (float*)bufA;              // x2l (f32)
  float* q1 = q0 + (size_t)NN * DOUT;    // x2r (f32)
  float* sk2 = (float*)bufC;             // skip2 (f32, fused path)
  float* alph1 = (float*)d_out;          // [E,4] logits
  float* alph2 = (float*)bufB;           // [E] logits
  // d_out tail (agg2 rewrites all of d_out at the very end):
  bf16* W1p = (bf16*)((char*)d_out + 5120000);   // 3 x 512x256 bf16
  bf16* W2p = W1p + (size_t)3 * D1 * FIN;        // 3 x 128x512 bf16

  // edge_index detect + convert
  zero_k<<<1, 256, 0, stream>>>(flag, 1);
  detflag_k<<<(EE + 255) / 256, 256, 0, stream>>>((const int*)ei, flag);
  conv_k<<<(EE + 255) / 256, 256, 0, stream>>>(ei, flag, srcD, dstD);

  // CSR build (by dst)
  zero_k<<<(NN + 255) / 256, 256, 0, stream>>>(deg, NN);
  hist_k<<<(EE + 255) / 256, 256, 0, stream>>>(dstD, deg, EE);
  scan_k<<<1, 1024, 0, stream>>>(deg, offs, cursor, NN);
  scatter_k<<<(EE + 255) / 256, 256, 0, stream>>>(dstD, cursor, elist, EE);

  if (fused) {
    // pack weights: W[K][Nc] f32 -> Wp[mat][col][k] bf16
    packT_k<<<dim3(D1 / 32, FIN / 32), 256, 0, stream>>>(W1l, W1p, D1, FIN);
    packT_k<<<dim3(D1 / 32, FIN / 32), 256, 0, stream>>>(
        W1r, W1p + (size_t)D1 * FIN, D1, FIN);
    packT_k<<<dim3(D1 / 32, FIN / 32), 256, 0, stream>>>(
        Wsk1, W1p + (size_t)2 * D1 * FIN, D1, FIN);
    packT_k<<<dim3(DOUT / 32, D1 / 32), 256, 0, stream>>>(W2l, W2p, DOUT, D1);
    packT_k<<<dim3(DOUT / 32, D1 / 32), 256, 0, stream>>>(
        W2r, W2p + (size_t)DOUT * D1, DOUT, D1);
    packT_k<<<dim3(DOUT / 32, D1 / 32), 256, 0, stream>>>(
        Wsk2, W2p + (size_t)2 * DOUT * D1, DOUT, D1);
    // layer-1 GEMM (bf16-A fast path when tier-3 workspace fits)
    if (fused3) {
      const long long n8 = (long long)NN * FIN / 8;  // 640000
      xpack_k<<<(unsigned)((n8 + 255) / 256), 256, 0, stream>>>(x, xbf, n8);
      gemm3p_t<bf16, bf16><<<dim3(D1 / 64, (NN + 63) / 64), 256, 0, stream>>>(
          xbf, W1p, b1l, b1r, bsk1, bufA, bufB, bufC, D1, FIN, NN);
    } else {
      gemm3p_t<float, bf16><<<dim3(D1 / 64, (NN + 63) / 64), 256, 0, stream>>>(
          x, W1p, b1l, b1r, bsk1, bufA, bufB, bufC, D1, FIN, NN);
    }
    if (fused2) {
      egather_k<<<EE / 128, 256, 0, stream>>>(eattr, elist, srcD, dstD,
                                              eacsr, s_csr, d_csr);
      alpha1c_k<<<EE / 128, 256, 0, stream>>>(bufA, bufB, eacsr, We1, att1,
                                              s_csr, d_csr, alph1);
      agg1c_k<<<(NN + 3) / 4, 256, 0, stream>>>(bufA, bufC, alph1, bias1, g1,
                                                be1, s_csr, offs, bufB);
      gemm3p_t<bf16, float><<<dim3(DOUT / 64, (NN + 63) / 64), 256, 0, stream>>>(
          bufB, W2p, b2l, b2r, bsk2, q0, q1, sk2, DOUT, D1, NN);
      alpha2c_k<<<EE / 128, 256, 0, stream>>>(q0, q1, eacsr, We2, att2,
                                              s_csr, d_csr, alph2);
      agg2c_k<<<(NN + 3) / 4, 256, 0, stream>>>(q0, sk2, alph2, bias2, g2, be2,
                                                s_csr, offs, (float*)d_out);
    } else {
      alpha1_k<<<EE / 128, 256, 0, stream>>>(bufA, bufB, eattr, We1, att1,
                                             srcD, dstD, alph1);
      agg1_k<<<(NN + 3) / 4, 256, 0, stream>>>(bufA, bufC, alph1, bias1, g1,
                                               be1, srcD, offs, elist, bufB);
      gemm3p_t<bf16, float><<<dim3(DOUT / 64, (NN + 63) / 64), 256, 0, stream>>>(
          bufB, W2p, b2l, b2r, bsk2, q0, q1, sk2, DOUT, D1, NN);
      alpha2_k<<<EE / 128, 256, 0, stream>>>(q0, q1, eattr, We2, att2,
                                             srcD, dstD, alph2);
      agg2_k<<<(NN + 3) / 4, 256, 0, stream>>>(q0, sk2, alph2, bias2, g2, be2,
                                               srcD, offs, elist, (float*)d_out);
    }
  } else {
    // r12 fallback path (fits in base_need bytes)
    (void)base_need;
    gemm2_t<float, bf16><<<dim3(D1 / 64, NN / 16), 256, 0, stream>>>(
        x, W1l, W1r, b1l, b1r, bufA, bufB, D1, FIN);
    l1_agg<<<NN, 256, 0, stream>>>(bufA, bufB, eattr, We1, att1, bias1,
                                   srcD, offs, elist, bufB);
    gemm_t<float, bf16, true><<<dim3(D1 / 64, NN / 16), 256, 0, stream>>>(
        x, Wsk1, bsk1, bufB, D1, FIN);
    lnelu_k<<<NN, 256, 0, stream>>>(bufB, g1, be1);
    gemm2_t<bf16, float><<<dim3(DOUT / 64, NN / 16), 256, 0, stream>>>(
        bufB, W2l, W2r, b2l, b2r, q0, q1, DOUT, D1);
    l2_agg<<<(NN + 3) / 4, 256, 0, stream>>>(q0, q1, eattr, We2, att2, bias2,
                                             srcD, offs, elist, q1);
    gemm_t<bf16, float, true><<<dim3(DOUT / 64, NN / 16), 256, 0, stream>>>(
        bufB, Wsk2, bsk2, q1, DOUT, D1);
    ln128_k<<<(NN + 3) / 4, 256, 0, stream>>>(q1, g2, be2, (float*)d_out);
  }

  (void)in_sizes; (void)n_in; (void)out_size;
}

// Round 10
// 625.582 us; speedup vs baseline: 1.0686x; 1.0686x over previous
//
#include <hip/hip_runtime.h>
#include <hip/hip_bf16.h>

typedef __bf16 bf16;
typedef __bf16 v8bf __attribute__((ext_vector_type(8)));
typedef float f32x4 __attribute__((ext_vector_type(4)));
typedef float f32x2 __attribute__((ext_vector_type(2)));

#define NN 20000
#define EE 320000
#define FIN 256
#define D1 512
#define DOUT 128
#define ED 26

__device__ __forceinline__ float b2f(bf16 x) { return (float)x; }

__device__ __forceinline__ f32x2 ldbf2v(const bf16* p) {
  unsigned int u;
  __builtin_memcpy(&u, p, 4);
  union { unsigned int i; float f; } lo, hi;
  lo.i = (u & 0xffffu) << 16;
  hi.i = u & 0xffff0000u;
  return (f32x2){lo.f, hi.f};
}

__device__ __forceinline__ f32x2 ldf2v(const float* p) {
  f32x2 t;
  __builtin_memcpy(&t, p, 8);
  return t;
}

__device__ __forceinline__ f32x4 ldf4v(const float* p) {
  f32x4 t;
  __builtin_memcpy(&t, p, 16);
  return t;
}

// ---------------- small utils ----------------
__global__ void zero_k(int* __restrict__ p, int n) {
  int i = blockIdx.x * 256 + threadIdx.x;
  if (i < n) p[i] = 0;
}

// ---------------- edge_index dtype detect + convert ------------------------
__global__ void detflag_k(const int* __restrict__ ei32, int* __restrict__ flag) {
  int i = blockIdx.x * 256 + threadIdx.x;
  int v = (i < EE) ? ei32[2 * i + 1] : 0;
  unsigned long long b = __ballot(v != 0);
  if ((threadIdx.x & 63) == 0 && b) atomicOr(flag, 1);
}

__global__ void conv_k(const void* __restrict__ ei, const int* __restrict__ flag,
                       int* __restrict__ src, int* __restrict__ dst) {
  int i = blockIdx.x * 256 + threadIdx.x;
  if (i >= EE) return;
  int s, d;
  if (*flag == 0) {
    const long long* p = (const long long*)ei;
    s = (int)p[i];
    d = (int)p[EE + i];
  } else {
    const int* p = (const int*)ei;
    s = p[i];
    d = p[EE + i];
  }
  src[i] = min(max(s, 0), NN - 1);
  dst[i] = min(max(d, 0), NN - 1);
}

// ---------------- CSR build ----------------
__global__ void hist_k(const int* __restrict__ dst, int* __restrict__ deg, int n) {
  int e = blockIdx.x * 256 + threadIdx.x;
  if (e < n) atomicAdd(&deg[dst[e]], 1);
}

__global__ __launch_bounds__(1024) void scan_k(const int* __restrict__ deg,
                                               int* __restrict__ offs,
                                               int* __restrict__ cursor, int n) {
  __shared__ int lsum[1024];
  int t = threadIdx.x;
  const int CH = (n + 1023) / 1024;
  int base = t * CH;
  int s = 0;
  for (int i = 0; i < CH; i++) {
    int idx = base + i;
    if (idx < n) s += deg[idx];
  }
  lsum[t] = s;
  __syncthreads();
  for (int o = 1; o < 1024; o <<= 1) {
    int v = (t >= o) ? lsum[t - o] : 0;
    __syncthreads();
    lsum[t] += v;
    __syncthreads();
  }
  int ex = (t == 0) ? 0 : lsum[t - 1];
  for (int i = 0; i < CH; i++) {
    int idx = base + i;
    if (idx < n) {
      offs[idx] = ex;
      cursor[idx] = ex;
      ex += deg[idx];
    }
  }
  if (t == 1023) offs[n] = lsum[1023];
}

__global__ void scatter_k(const int* __restrict__ dst, int* __restrict__ cursor,
                          int* __restrict__ elist, int n) {
  int e = blockIdx.x * 256 + threadIdx.x;
  if (e < n) {
    int p = atomicAdd(&cursor[dst[e]], 1);
    if ((unsigned)p < (unsigned)EE) elist[p] = e;
  }
}

// ------- CSR-order gather of edge data: eatt rows (bf16, K-pad 32), src, dst
__global__ __launch_bounds__(256) void egather_k(
    const float* __restrict__ eatt, const int* __restrict__ elist,
    const int* __restrict__ srcs, const int* __restrict__ dsts,
    bf16* __restrict__ ea_csr, int* __restrict__ s_csr,
    int* __restrict__ d_csr) {
  __shared__ int e_s[128];
  int tid = threadIdx.x;
  int base = blockIdx.x * 128;  // EE = 2500 * 128
  if (tid < 128) {
    int e = elist[base + tid];
    e = min(max(e, 0), EE - 1);
    e_s[tid] = e;
    s_csr[base + tid] = srcs[e];
    d_csr[base + tid] = dsts[e];
  }
  __syncthreads();
  for (int idx = tid; idx < 128 * 32; idx += 256) {
    int i = idx >> 5, k = idx & 31;
    float v = (k < 26) ? eatt[(size_t)e_s[i] * ED + k] : 0.f;
    ea_csr[(size_t)(base + i) * 32 + k] = (bf16)v;
  }
}

// ------- x pre-pack: f32 -> bf16, same row-major layout --------------------
__global__ __launch_bounds__(256) void xpack_k(const float* __restrict__ x,
                                               bf16* __restrict__ xbf,
                                               long long n8) {
  long long i = (long long)blockIdx.x * 256 + threadIdx.x;
  if (i >= n8) return;
  const float* ap = x + i * 8;
  f32x4 u, v;
  __builtin_memcpy(&u, ap, 16);
  __builtin_memcpy(&v, ap + 4, 16);
  v8bf o;
#pragma unroll
  for (int j = 0; j < 4; j++) {
    o[j] = (bf16)u[j];
    o[4 + j] = (bf16)v[j];
  }
  __builtin_memcpy(xbf + i * 8, &o, 16);
}

// ------- weight pack: W [K][Nc] f32 -> Bp [Nc][K] bf16 (LDS tile transpose) -
__global__ __launch_bounds__(256) void packT_k(const float* __restrict__ W,
                                               bf16* __restrict__ Bp,
                                               int Nc, int K) {
  __shared__ float t[32][33];
  int c0 = blockIdx.x * 32, k0 = blockIdx.y * 32;
  int tr = threadIdx.x >> 5, tc = threadIdx.x & 31;
#pragma unroll
  for (int i = 0; i < 32; i += 8)
    t[tr + i][tc] = W[(size_t)(k0 + tr + i) * Nc + c0 + tc];
  __syncthreads();
#pragma unroll
  for (int i = 0; i < 32; i += 8)
    Bp[(size_t)(c0 + tr + i) * K + k0 + tc] = (bf16)t[tc][tr + i];
}

// ------- We pack into MFMA B-fragment order --------------------------------
// Wp[((ng*4+quad)*16+lc)*8+j] = We[quad*8+j][ng*16+lc] (0 for k>=26).
// Launch with exactly (Nc/16)*512 threads (multiple of 256).
__global__ __launch_bounds__(256) void packWe_k(const float* __restrict__ We,
                                                bf16* __restrict__ Wp, int Nc) {
  int o = blockIdx.x * 256 + threadIdx.x;
  int j = o & 7;
  int lc = (o >> 3) & 15;
  int quad = (o >> 7) & 3;
  int ng = o >> 9;
  int k = quad * 8 + j;
  int col = ng * 16 + lc;
  float v = (k < 26) ? We[(size_t)k * Nc + col] : 0.f;
  Wp[o] = (bf16)v;
}

// ------- MFMA GEMM (single-output, for fallback skip ADD) ------------------
template <typename TA, typename TO, bool ADD>
__global__ __launch_bounds__(256) void gemm_t(const TA* __restrict__ A,
                                              const float* __restrict__ B,
                                              const float* __restrict__ bias,
                                              TO* out, int Nc, int K) {
  int w = threadIdx.x >> 6;
  int l = threadIdx.x & 63;
  int quad = l >> 4;
  int mrow = blockIdx.y * 16 + (l & 15);
  int col = blockIdx.x * 64 + w * 16 + (l & 15);
  f32x4 acc = {0.f, 0.f, 0.f, 0.f};
  for (int k0 = 0; k0 < K; k0 += 32) {
    int ka = k0 + quad * 8;
    v8bf a, b;
    if constexpr (sizeof(TA) == 4) {
      const float* ap = (const float*)A + (size_t)mrow * K + ka;
#pragma unroll
      for (int j = 0; j < 8; j++) a[j] = (bf16)ap[j];
    } else {
      __builtin_memcpy(&a, (const bf16*)A + (size_t)mrow * K + ka, 16);
    }
#pragma unroll
    for (int j = 0; j < 8; j++) b[j] = (bf16)B[(size_t)(ka + j) * Nc + col];
    acc = __builtin_amdgcn_mfma_f32_16x16x32_bf16(a, b, acc, 0, 0, 0);
  }
  float bb = bias[col];
  int obase = blockIdx.y * 16 + quad * 4;
#pragma unroll
  for (int r = 0; r < 4; r++) {
    size_t idx = (size_t)(obase + r) * Nc + col;
    float v = acc[r] + bb;
    if (ADD) v += (float)out[idx];
    out[idx] = (TO)v;
  }
}

// ------- 2-output fused MFMA GEMM (fallback path) --------------------------
template <typename TA, typename TO>
__global__ __launch_bounds__(256) void gemm2_t(const TA* __restrict__ A,
                                               const float* __restrict__ B0,
                                               const float* __restrict__ B1,
                                               const float* __restrict__ bias0,
                                               const float* __restrict__ bias1,
                                               TO* __restrict__ out0,
                                               TO* __restrict__ out1,
                                               int Nc, int K) {
  int w = threadIdx.x >> 6;
  int l = threadIdx.x & 63;
  int quad = l >> 4;
  int mrow = blockIdx.y * 16 + (l & 15);
  int col = blockIdx.x * 64 + w * 16 + (l & 15);
  f32x4 acc0 = {0.f, 0.f, 0.f, 0.f};
  f32x4 acc1 = {0.f, 0.f, 0.f, 0.f};
  for (int k0 = 0; k0 < K; k0 += 32) {
    int ka = k0 + quad * 8;
    v8bf a, b0, b1;
    if constexpr (sizeof(TA) == 4) {
      const float* ap = (const float*)A + (size_t)mrow * K + ka;
#pragma unroll
      for (int j = 0; j < 8; j++) a[j] = (bf16)ap[j];
    } else {
      __builtin_memcpy(&a, (const bf16*)A + (size_t)mrow * K + ka, 16);
    }
#pragma unroll
    for (int j = 0; j < 8; j++) {
      size_t bi = (size_t)(ka + j) * Nc + col;
      b0[j] = (bf16)B0[bi];
      b1[j] = (bf16)B1[bi];
    }
    acc0 = __builtin_amdgcn_mfma_f32_16x16x32_bf16(a, b0, acc0, 0, 0, 0);
    acc1 = __builtin_amdgcn_mfma_f32_16x16x32_bf16(a, b1, acc1, 0, 0, 0);
  }
  float bb0 = bias0[col], bb1 = bias1[col];
  int obase = blockIdx.y * 16 + quad * 4;
#pragma unroll
  for (int r = 0; r < 4; r++) {
    size_t idx = (size_t)(obase + r) * Nc + col;
    out0[idx] = (TO)(acc0[r] + bb0);
    out1[idx] = (TO)(acc1[r] + bb1);
  }
}

// ------- 3-output packed-B MFMA GEMM: 64x64 tile, 4 M-subtiles/wave --------
template <typename TA, typename TO>
__global__ __launch_bounds__(256) void gemm3p_t(
    const TA* __restrict__ A, const bf16* __restrict__ Bp,
    const float* __restrict__ bias0, const float* __restrict__ bias1,
    const float* __restrict__ bias2, TO* __restrict__ out0,
    TO* __restrict__ out1, TO* __restrict__ out2, int Nc, int K, int M) {
  int w = threadIdx.x >> 6;
  int l = threadIdx.x & 63;
  int quad = l >> 4, lc = l & 15;
  int col = blockIdx.x * 64 + w * 16 + lc;
  int mbase = blockIdx.y * 64;
  const bf16* b0p = Bp + (size_t)col * K;
  const bf16* b1p = Bp + ((size_t)Nc + col) * K;
  const bf16* b2p = Bp + ((size_t)2 * Nc + col) * K;
  f32x4 acc[4][3];
#pragma unroll
  for (int i = 0; i < 4; i++)
#pragma unroll
    for (int j = 0; j < 3; j++) acc[i][j] = (f32x4){0.f, 0.f, 0.f, 0.f};
  for (int k0 = 0; k0 < K; k0 += 32) {
    int ka = k0 + quad * 8;
    v8bf b0, b1, b2;
    __builtin_memcpy(&b0, b0p + ka, 16);
    __builtin_memcpy(&b1, b1p + ka, 16);
    __builtin_memcpy(&b2, b2p + ka, 16);
#pragma unroll
    for (int ms = 0; ms < 4; ms++) {
      int row = min(mbase + ms * 16 + lc, M - 1);
      v8bf a;
      if constexpr (sizeof(TA) == 4) {
        const float* ap = (const float*)A + (size_t)row * K + ka;
        f32x4 u, v;
        __builtin_memcpy(&u, ap, 16);
        __builtin_memcpy(&v, ap + 4, 16);
#pragma unroll
        for (int j = 0; j < 4; j++) {
          a[j] = (bf16)u[j];
          a[4 + j] = (bf16)v[j];
        }
      } else {
        __builtin_memcpy(&a, (const bf16*)A + (size_t)row * K + ka, 16);
      }
      acc[ms][0] = __builtin_amdgcn_mfma_f32_16x16x32_bf16(a, b0, acc[ms][0], 0, 0, 0);
      acc[ms][1] = __builtin_amdgcn_mfma_f32_16x16x32_bf16(a, b1, acc[ms][1], 0, 0, 0);
      acc[ms][2] = __builtin_amdgcn_mfma_f32_16x16x32_bf16(a, b2, acc[ms][2], 0, 0, 0);
    }
  }
  float bb0 = bias0[col], bb1 = bias1[col], bb2 = bias2[col];
#pragma unroll
  for (int ms = 0; ms < 4; ms++) {
    int ob = mbase + ms * 16 + quad * 4;
#pragma unroll
    for (int r = 0; r < 4; r++) {
      int orow = ob + r;
      if (orow < M) {
        size_t idx = (size_t)orow * Nc + col;
        out0[idx] = (TO)(acc[ms][0][r] + bb0);
        out1[idx] = (TO)(acc[ms][1][r] + bb1);
        out2[idx] = (TO)(acc[ms][2][r] + bb2);
      }
    }
  }
}

// ==== TIER-2: CSR-order MFMA alpha (R8-measured-best epilogue form) ========
// bfrag setup from pre-packed Wp (contiguous 16B fragment loads).
__global__ __launch_bounds__(256) void alpha1c_k(
    const bf16* __restrict__ xl, const bf16* __restrict__ xr,
    const bf16* __restrict__ ea_csr, const bf16* __restrict__ Wp,
    const float* __restrict__ att, const int* __restrict__ s_csr,
    const int* __restrict__ d_csr, float* __restrict__ alphap) {
  __shared__ bf16 ea_s[128 * 40];
  int tid = threadIdx.x;
  int w = __builtin_amdgcn_readfirstlane(tid >> 6);
  int l = tid & 63;
  int quad = l >> 4, lc = l & 15;
  int base = blockIdx.x * 128;
  for (int idx = tid; idx < 1024; idx += 256) {
    int i = idx >> 3, k4 = (idx & 7) * 4;
    unsigned long long v;
    __builtin_memcpy(&v, ea_csr + (size_t)(base + i) * 32 + k4, 8);
    __builtin_memcpy(&ea_s[i * 40 + k4], &v, 8);
  }
  int c0 = w * 128;
  v8bf bfrag[8];
  float av[8];
#pragma unroll
  for (int n = 0; n < 8; n++) {
    int col = c0 + n * 16 + lc;
    av[n] = att[col];
    __builtin_memcpy(&bfrag[n],
                     Wp + ((size_t)((w * 8 + n) * 4 + quad) * 16 + lc) * 8, 16);
  }
  __syncthreads();
#pragma unroll 1
  for (int m = 0; m < 8; m++) {
    v8bf afrag;
    __builtin_memcpy(&afrag, &ea_s[(m * 16 + lc) * 40 + quad * 8], 16);
    f32x4 z = {0.f, 0.f, 0.f, 0.f};
    f32x4 acc[8];
#pragma unroll
    for (int n = 0; n < 8; n++)
      acc[n] = __builtin_amdgcn_mfma_f32_16x16x32_bf16(afrag, bfrag[n], z, 0, 0, 0);
    int e0 = base + m * 16 + quad * 4;
    int sA[4], dA[4];
#pragma unroll
    for (int r = 0; r < 4; r++) {
      sA[r] = s_csr[e0 + r];
      dA[r] = d_csr[e0 + r];
    }
    f32x4 pal = {0.f, 0.f, 0.f, 0.f};
#pragma unroll
    for (int n = 0; n < 8; n++) {
      int col = c0 + n * 16 + lc;
#pragma unroll
      for (int r = 0; r < 4; r++) {
        float mm = (float)xl[(size_t)sA[r] * D1 + col] +
                   (float)xr[(size_t)dA[r] * D1 + col] + acc[n][r];
        mm = fmaxf(mm, 0.f) + 0.2f * fminf(mm, 0.f);
        pal[r] += mm * av[n];
      }
    }
#pragma unroll
    for (int o = 1; o < 16; o <<= 1) {
      pal[0] += __shfl_xor(pal[0], o, 64);
      pal[1] += __shfl_xor(pal[1], o, 64);
      pal[2] += __shfl_xor(pal[2], o, 64);
      pal[3] += __shfl_xor(pal[3], o, 64);
    }
    if (lc == 0) {
#pragma unroll
      for (int r = 0; r < 4; r++) alphap[(size_t)(e0 + r) * 4 + w] = pal[r];
    }
  }
}

__global__ __launch_bounds__(256) void alpha2c_k(
    const float* __restrict__ xl, const float* __restrict__ xr,
    const bf16* __restrict__ ea_csr, const bf16* __restrict__ Wp,
    const float* __restrict__ att, const int* __restrict__ s_csr,
    const int* __restrict__ d_csr, float* __restrict__ alphap) {
  __shared__ bf16 ea_s[128 * 40];
  __shared__ float pal_s[4 * 128];
  int tid = threadIdx.x;
  int w = __builtin_amdgcn_readfirstlane(tid >> 6);
  int l = tid & 63;
  int quad = l >> 4, lc = l & 15;
  int base = blockIdx.x * 128;
  for (int idx = tid; idx < 1024; idx += 256) {
    int i = idx >> 3, k4 = (idx & 7) * 4;
    unsigned long long v;
    __builtin_memcpy(&v, ea_csr + (size_t)(base + i) * 32 + k4, 8);
    __builtin_memcpy(&ea_s[i * 40 + k4], &v, 8);
  }
  int c0 = w * 32;
  v8bf bfrag[2];
  float av[2];
#pragma unroll
  for (int n = 0; n < 2; n++) {
    int col = c0 + n * 16 + lc;
    av[n] = att[col];
    __builtin_memcpy(&bfrag[n],
                     Wp + ((size_t)((w * 2 + n) * 4 + quad) * 16 + lc) * 8, 16);
  }
  __syncthreads();
#pragma unroll 1
  for (int m = 0; m < 8; m++) {
    v8bf afrag;
    __builtin_memcpy(&afrag, &ea_s[(m * 16 + lc) * 40 + quad * 8], 16);
    f32x4 z = {0.f, 0.f, 0.f, 0.f};
    f32x4 acc[2];
#pragma unroll
    for (int n = 0; n < 2; n++)
      acc[n] = __builtin_amdgcn_mfma_f32_16x16x32_bf16(afrag, bfrag[n], z, 0, 0, 0);
    int e0 = base + m * 16 + quad * 4;
    int sA[4], dA[4];
#pragma unroll
    for (int r = 0; r < 4; r++) {
      sA[r] = s_csr[e0 + r];
      dA[r] = d_csr[e0 + r];
    }
    f32x4 pal = {0.f, 0.f, 0.f, 0.f};
#pragma unroll
    for (int n = 0; n < 2; n++) {
      int col = c0 + n * 16 + lc;
#pragma unroll
      for (int r = 0; r < 4; r++) {
        float mm = xl[(size_t)sA[r] * DOUT + col] +
                   xr[(size_t)dA[r] * DOUT + col] + acc[n][r];
        mm = fmaxf(mm, 0.f) + 0.2f * fminf(mm, 0.f);
        pal[r] += mm * av[n];
      }
    }
#pragma unroll
    for (int o = 1; o < 16; o <<= 1) {
      pal[0] += __shfl_xor(pal[0], o, 64);
      pal[1] += __shfl_xor(pal[1], o, 64);
      pal[2] += __shfl_xor(pal[2], o, 64);
      pal[3] += __shfl_xor(pal[3], o, 64);
    }
    if (lc == 0) {
      int eb = m * 16 + quad * 4;
#pragma unroll
      for (int r = 0; r < 4; r++) pal_s[w * 128 + eb + r] = pal[r];
    }
  }
  __syncthreads();
  if (tid < 128) {
    float a = pal_s[tid] + pal_s[128 + tid] + pal_s[256 + tid] + pal_s[384 + tid];
    alphap[base + tid] = a;
  }
}

// ==== TIER-2 aggs: wave-per-node, contiguous alpha/s reads, lane-par max ===
__global__ __launch_bounds__(256) void agg1c_k(
    const bf16* __restrict__ xl, const bf16* __restrict__ skip,
    const float* __restrict__ alphap, const float* __restrict__ bias,
    const float* __restrict__ g, const float* __restrict__ be,
    const int* __restrict__ s_csr, const int* __restrict__ offs,
    bf16* __restrict__ hout) {
  int tid = threadIdx.x;
  int w = tid >> 6, l = tid & 63;
  int node = blockIdx.x * 4 + w;
  if (node >= NN) return;
  int c = l * 8;
  int head = l >> 4;
  int i0 = offs[node], i1 = offs[node + 1];
  i0 = max(0, min(i0, EE));
  i1 = max(i0, min(i1, EE));
  float m = -3.0e38f;
  for (int i = i0 + (l & 15); i < i1; i += 16)
    m = fmaxf(m, alphap[(size_t)i * 4 + head]);
#pragma unroll
  for (int o = 1; o < 16; o <<= 1) m = fmaxf(m, __shfl_xor(m, o, 64));
  float den = 0.f;
  f32x4 a0 = {0.f, 0.f, 0.f, 0.f}, a1 = {0.f, 0.f, 0.f, 0.f};
  int s = 0;
  float al = 0.f;
  if (i0 < i1) {
    s = __builtin_amdgcn_readfirstlane(s_csr[i0]);
    al = alphap[(size_t)i0 * 4 + head];
  }
  for (int i = i0; i < i1; i++) {
    int s_n = s;
    float al_n = al;
    if (i + 1 < i1) {
      s_n = __builtin_amdgcn_readfirstlane(s_csr[i + 1]);
      al_n = alphap[(size_t)(i + 1) * 4 + head];
    }
    float pr = __expf(al - m);
    den += pr;
    v8bf xv;
    __builtin_memcpy(&xv, xl + (size_t)s * D1 + c, 16);
#pragma unroll
    for (int j = 0; j < 4; j++) {
      a0[j] += pr * (float)xv[j];
      a1[j] += pr * (float)xv[4 + j];
    }
    s = s_n;
    al = al_n;
  }
  float inv = 1.f / (den + 1e-16f);
  v8bf skv;
  __builtin_memcpy(&skv, skip + (size_t)node * D1 + c, 16);
  f32x4 bv0 = ldf4v(bias + c), bv1 = ldf4v(bias + c + 4);
  float o[8];
#pragma unroll
  for (int j = 0; j < 4; j++) {
    o[j] = a0[j] * inv + bv0[j] + (float)skv[j];
    o[4 + j] = a1[j] * inv + bv1[j] + (float)skv[4 + j];
  }
  float s1 = 0.f, s2 = 0.f;
#pragma unroll
  for (int j = 0; j < 8; j++) {
    s1 += o[j];
    s2 += o[j] * o[j];
  }
#pragma unroll
  for (int of = 32; of; of >>= 1) {
    s1 += __shfl_xor(s1, of, 64);
    s2 += __shfl_xor(s2, of, 64);
  }
  float mu = s1 * (1.f / 512.f);
  float var = fmaxf(s2 * (1.f / 512.f) - mu * mu, 0.f);
  float rs = rsqrtf(var + 1e-5f);
  f32x4 gv0 = ldf4v(g + c), gv1 = ldf4v(g + c + 4);
  f32x4 ev0 = ldf4v(be + c), ev1 = ldf4v(be + c + 4);
  v8bf hv;
#pragma unroll
  for (int j = 0; j < 4; j++) {
    float y0 = (o[j] - mu) * rs * gv0[j] + ev0[j];
    float y1 = (o[4 + j] - mu) * rs * gv1[j] + ev1[j];
    y0 = y0 > 0.f ? y0 : __expf(fminf(y0, 0.f)) - 1.f;
    y1 = y1 > 0.f ? y1 : __expf(fminf(y1, 0.f)) - 1.f;
    hv[j] = (bf16)y0;
    hv[4 + j] = (bf16)y1;
  }
  __builtin_memcpy(hout + (size_t)node * D1 + c, &hv, 16);
}

__global__ __launch_bounds__(256) void agg2c_k(
    const float* __restrict__ xl, const float* __restrict__ skip,
    const float* __restrict__ alphap, const float* __restrict__ bias,
    const float* __restrict__ g, const float* __restrict__ be,
    const int* __restrict__ s_csr, const int* __restrict__ offs,
    float* __restrict__ outp) {
  int tid = threadIdx.x;
  int w = tid >> 6, l = tid & 63;
  int node = blockIdx.x * 4 + w;
  if (node >= NN) return;
  int c = 2 * l;
  int i0 = offs[node], i1 = offs[node + 1];
  i0 = max(0, min(i0, EE));
  i1 = max(i0, min(i1, EE));
  float m = -3.0e38f;
  for (int i = i0 + l; i < i1; i += 64) m = fmaxf(m, alphap[i]);
#pragma unroll
  for (int o = 32; o; o >>= 1) m = fmaxf(m, __shfl_xor(m, o, 64));
  float den = 0.f;
  f32x2 acc = {0.f, 0.f};
  int s = 0;
  float al = 0.f;
  if (i0 < i1) {
    s = __builtin_amdgcn_readfirstlane(s_csr[i0]);
    al = alphap[i0];
  }
  for (int i = i0; i < i1; i++) {
    int s_n = s;
    float al_n = al;
    if (i + 1 < i1) {
      s_n = __builtin_amdgcn_readfirstlane(s_csr[i + 1]);
      al_n = alphap[i + 1];
    }
    float pr = __expf(al - m);
    den += pr;
    f32x2 xv = ldf2v(xl + (size_t)s * DOUT + c);
    acc += (f32x2){pr, pr} * xv;
    s = s_n;
    al = al_n;
  }
  float inv = 1.f / (den + 1e-16f);
  f32x2 sk = ldf2v(skip + (size_t)node * DOUT + c);
  float o0 = acc.x * inv + bias[c] + sk.x;
  float o1 = acc.y * inv + bias[c + 1] + sk.y;
  float s1 = o0 + o1, s2 = o0 * o0 + o1 * o1;
#pragma unroll
  for (int of = 32; of; of >>= 1) {
    s1 += __shfl_xor(s1, of, 64);
    s2 += __shfl_xor(s2, of, 64);
  }
  float mu = s1 * (1.f / 128.f);
  float var = fmaxf(s2 * (1.f / 128.f) - mu * mu, 0.f);
  float rs = rsqrtf(var + 1e-5f);
  outp[(size_t)node * DOUT + c] = (o0 - mu) * rs * g[c] + be[c];
  outp[(size_t)node * DOUT + c + 1] = (o1 - mu) * rs * g[c + 1] + be[c + 1];
}

// ==== TIER-1 (R6) kernels: edge-order alpha + elist-indirect aggs ==========
__global__ __launch_bounds__(256) void alpha1_k(
    const bf16* __restrict__ xl, const bf16* __restrict__ xr,
    const float* __restrict__ eatt, const float* __restrict__ We,
    const float* __restrict__ att, const int* __restrict__ srcs,
    const int* __restrict__ dsts, float* __restrict__ alpha) {
  __shared__ bf16 ea_s[128 * 40];
  int tid = threadIdx.x;
  int w = __builtin_amdgcn_readfirstlane(tid >> 6);
  int l = tid & 63;
  int quad = l >> 4, lc = l & 15;
  int base = blockIdx.x * 128;
  for (int i = tid; i < 128 * 32; i += 256) {
    int e = i >> 5, k = i & 31;
    float v = (k < 26) ? eatt[(size_t)(base + e) * ED + k] : 0.f;
    ea_s[e * 40 + k] = (bf16)v;
  }
  int c0 = w * 128;
  v8bf bfrag[8];
  float av[8];
#pragma unroll
  for (int n = 0; n < 8; n++) {
    int col = c0 + n * 16 + lc;
    av[n] = att[col];
#pragma unroll
    for (int j = 0; j < 8; j++) {
      int k = quad * 8 + j;
      bfrag[n][j] = (k < 26) ? (bf16)We[(size_t)k * D1 + col] : (bf16)0.f;
    }
  }
  __syncthreads();
#pragma unroll 1
  for (int m = 0; m < 8; m++) {
    v8bf afrag;
    __builtin_memcpy(&afrag, &ea_s[(m * 16 + lc) * 40 + quad * 8], 16);
    f32x4 z = {0.f, 0.f, 0.f, 0.f};
    f32x4 acc[8];
#pragma unroll
    for (int n = 0; n < 8; n++)
      acc[n] = __builtin_amdgcn_mfma_f32_16x16x32_bf16(afrag, bfrag[n], z, 0, 0, 0);
    int e0 = base + m * 16 + quad * 4;
    int sA[4], dA[4];
#pragma unroll
    for (int r = 0; r < 4; r++) {
      sA[r] = srcs[e0 + r];
      dA[r] = dsts[e0 + r];
    }
    f32x4 pal = {0.f, 0.f, 0.f, 0.f};
#pragma unroll
    for (int n = 0; n < 8; n++) {
      int col = c0 + n * 16 + lc;
#pragma unroll
      for (int r = 0; r < 4; r++) {
        float mm = (float)xl[(size_t)sA[r] * D1 + col] +
                   (float)xr[(size_t)dA[r] * D1 + col] + acc[n][r];
        mm = fmaxf(mm, 0.f) + 0.2f * fminf(mm, 0.f);
        pal[r] += mm * av[n];
      }
    }
#pragma unroll
    for (int o = 1; o < 16; o <<= 1) {
      pal[0] += __shfl_xor(pal[0], o, 64);
      pal[1] += __shfl_xor(pal[1], o, 64);
      pal[2] += __shfl_xor(pal[2], o, 64);
      pal[3] += __shfl_xor(pal[3], o, 64);
    }
    if (lc == 0) {
#pragma unroll
      for (int r = 0; r < 4; r++) alpha[(size_t)(e0 + r) * 4 + w] = pal[r];
    }
  }
}

__global__ __launch_bounds__(256) void alpha2_k(
    const float* __restrict__ xl, const float* __restrict__ xr,
    const float* __restrict__ eatt, const float* __restrict__ We,
    const float* __restrict__ att, const int* __restrict__ srcs,
    const int* __restrict__ dsts, float* __restrict__ alpha) {
  __shared__ bf16 ea_s[128 * 40];
  __shared__ float pal_s[4 * 128];
  int tid = threadIdx.x;
  int w = __builtin_amdgcn_readfirstlane(tid >> 6);
  int l = tid & 63;
  int quad = l >> 4, lc = l & 15;
  int base = blockIdx.x * 128;
  for (int i = tid; i < 128 * 32; i += 256) {
    int e = i >> 5, k = i & 31;
    float v = (k < 26) ? eatt[(size_t)(base + e) * ED + k] : 0.f;
    ea_s[e * 40 + k] = (bf16)v;
  }
  int c0 = w * 32;
  v8bf bfrag[2];
  float av[2];
#pragma unroll
  for (int n = 0; n < 2; n++) {
    int col = c0 + n * 16 + lc;
    av[n] = att[col];
#pragma unroll
    for (int j = 0; j < 8; j++) {
      int k = quad * 8 + j;
      bfrag[n][j] = (k < 26) ? (bf16)We[(size_t)k * DOUT + col] : (bf16)0.f;
    }
  }
  __syncthreads();
#pragma unroll 1
  for (int m = 0; m < 8; m++) {
    v8bf afrag;
    __builtin_memcpy(&afrag, &ea_s[(m * 16 + lc) * 40 + quad * 8], 16);
    f32x4 z = {0.f, 0.f, 0.f, 0.f};
    f32x4 acc[2];
#pragma unroll
    for (int n = 0; n < 2; n++)
      acc[n] = __builtin_amdgcn_mfma_f32_16x16x32_bf16(afrag, bfrag[n], z, 0, 0, 0);
    int e0 = base + m * 16 + quad * 4;
    int sA[4], dA[4];
#pragma unroll
    for (int r = 0; r < 4; r++) {
      sA[r] = srcs[e0 + r];
      dA[r] = dsts[e0 + r];
    }
    f32x4 pal = {0.f, 0.f, 0.f, 0.f};
#pragma unroll
    for (int n = 0; n < 2; n++) {
      int col = c0 + n * 16 + lc;
#pragma unroll
      for (int r = 0; r < 4; r++) {
        float mm = xl[(size_t)sA[r] * DOUT + col] +
                   xr[(size_t)dA[r] * DOUT + col] + acc[n][r];
        mm = fmaxf(mm, 0.f) + 0.2f * fminf(mm, 0.f);
        pal[r] += mm * av[n];
      }
    }
#pragma unroll
    for (int o = 1; o < 16; o <<= 1) {
      pal[0] += __shfl_xor(pal[0], o, 64);
      pal[1] += __shfl_xor(pal[1], o, 64);
      pal[2] += __shfl_xor(pal[2], o, 64);
      pal[3] += __shfl_xor(pal[3], o, 64);
    }
    if (lc == 0) {
      int eb = m * 16 + quad * 4;
#pragma unroll
      for (int r = 0; r < 4; r++) pal_s[w * 128 + eb + r] = pal[r];
    }
  }
  __syncthreads();
  if (tid < 128) {
    float a = pal_s[tid] + pal_s[128 + tid] + pal_s[256 + tid] + pal_s[384 + tid];
    alpha[base + tid] = a;
  }
}

__global__ __launch_bounds__(256) void agg1_k(
    const bf16* __restrict__ xl, const bf16* __restrict__ skip,
    const float* __restrict__ alpha, const float* __restrict__ bias,
    const float* __restrict__ g, const float* __restrict__ be,
    const int* __restrict__ srcs, const int* __restrict__ offs,
    const int* __restrict__ elist, bf16* __restrict__ hout) {
  int tid = threadIdx.x;
  int w = tid >> 6, l = tid & 63;
  int node = blockIdx.x * 4 + w;
  if (node >= NN) return;
  int c = l * 8;
  int head = l >> 4;
  int i0 = offs[node], i1 = offs[node + 1];
  i0 = max(0, min(i0, EE));
  i1 = max(i0, min(i1, EE));
  float m = -3.0e38f;
  for (int i = i0; i < i1; i++) {
    int e = __builtin_amdgcn_readfirstlane(elist[i]);
    m = fmaxf(m, alpha[(size_t)e * 4 + head]);
  }
  float den = 0.f;
  f32x4 a0 = {0.f, 0.f, 0.f, 0.f}, a1 = {0.f, 0.f, 0.f, 0.f};
  int s = 0;
  float al = 0.f;
  if (i0 < i1) {
    int e = __builtin_amdgcn_readfirstlane(elist[i0]);
    s = __builtin_amdgcn_readfirstlane(srcs[e]);
    al = alpha[(size_t)e * 4 + head];
  }
  for (int i = i0; i < i1; i++) {
    int s_n = s;
    float al_n = al;
    if (i + 1 < i1) {
      int e = __builtin_amdgcn_readfirstlane(elist[i + 1]);
      s_n = __builtin_amdgcn_readfirstlane(srcs[e]);
      al_n = alpha[(size_t)e * 4 + head];
    }
    float pr = __expf(al - m);
    den += pr;
    v8bf xv;
    __builtin_memcpy(&xv, xl + (size_t)s * D1 + c, 16);
#pragma unroll
    for (int j = 0; j < 4; j++) {
      a0[j] += pr * (float)xv[j];
      a1[j] += pr * (float)xv[4 + j];
    }
    s = s_n;
    al = al_n;
  }
  float inv = 1.f / (den + 1e-16f);
  v8bf skv;
  __builtin_memcpy(&skv, skip + (size_t)node * D1 + c, 16);
  f32x4 bv0 = ldf4v(bias + c), bv1 = ldf4v(bias + c + 4);
  float o[8];
#pragma unroll
  for (int j = 0; j < 4; j++) {
    o[j] = a0[j] * inv + bv0[j] + (float)skv[j];
    o[4 + j] = a1[j] * inv + bv1[j] + (float)skv[4 + j];
  }
  float s1 = 0.f, s2 = 0.f;
#pragma unroll
  for (int j = 0; j < 8; j++) {
    s1 += o[j];
    s2 += o[j] * o[j];
  }
#pragma unroll
  for (int of = 32; of; of >>= 1) {
    s1 += __shfl_xor(s1, of, 64);
    s2 += __shfl_xor(s2, of, 64);
  }
  float mu = s1 * (1.f / 512.f);
  float var = fmaxf(s2 * (1.f / 512.f) - mu * mu, 0.f);
  float rs = rsqrtf(var + 1e-5f);
  f32x4 gv0 = ldf4v(g + c), gv1 = ldf4v(g + c + 4);
  f32x4 ev0 = ldf4v(be + c), ev1 = ldf4v(be + c + 4);
  v8bf hv;
#pragma unroll
  for (int j = 0; j < 4; j++) {
    float y0 = (o[j] - mu) * rs * gv0[j] + ev0[j];
    float y1 = (o[4 + j] - mu) * rs * gv1[j] + ev1[j];
    y0 = y0 > 0.f ? y0 : __expf(fminf(y0, 0.f)) - 1.f;
    y1 = y1 > 0.f ? y1 : __expf(fminf(y1, 0.f)) - 1.f;
    hv[j] = (bf16)y0;
    hv[4 + j] = (bf16)y1;
  }
  __builtin_memcpy(hout + (size_t)node * D1 + c, &hv, 16);
}

__global__ __launch_bounds__(256) void agg2_k(
    const float* __restrict__ xl, const float* __restrict__ skip,
    const float* __restrict__ alpha, const float* __restrict__ bias,
    const float* __restrict__ g, const float* __restrict__ be,
    const int* __restrict__ srcs, const int* __restrict__ offs,
    const int* __restrict__ elist, float* __restrict__ outp) {
  int tid = threadIdx.x;
  int w = tid >> 6, l = tid & 63;
  int node = blockIdx.x * 4 + w;
  if (node >= NN) return;
  int c = 2 * l;
  int i0 = offs[node], i1 = offs[node + 1];
  i0 = max(0, min(i0, EE));
  i1 = max(i0, min(i1, EE));
  float m = -3.0e38f;
  for (int i = i0; i < i1; i++) {
    int e = __builtin_amdgcn_readfirstlane(elist[i]);
    m = fmaxf(m, alpha[e]);
  }
  float den = 0.f;
  f32x2 acc = {0.f, 0.f};
  int s = 0;
  float al = 0.f;
  if (i0 < i1) {
    int e = __builtin_amdgcn_readfirstlane(elist[i0]);
    s = __builtin_amdgcn_readfirstlane(srcs[e]);
    al = alpha[e];
  }
  for (int i = i0; i < i1; i++) {
    int s_n = s;
    float al_n = al;
    if (i + 1 < i1) {
      int e = __builtin_amdgcn_readfirstlane(elist[i + 1]);
      s_n = __builtin_amdgcn_readfirstlane(srcs[e]);
      al_n = alpha[e];
    }
    float pr = __expf(al - m);
    den += pr;
    f32x2 xv = ldf2v(xl + (size_t)s * DOUT + c);
    acc += (f32x2){pr, pr} * xv;
    s = s_n;
    al = al_n;
  }
  float inv = 1.f / (den + 1e-16f);
  f32x2 sk = ldf2v(skip + (size_t)node * DOUT + c);
  float o0 = acc.x * inv + bias[c] + sk.x;
  float o1 = acc.y * inv + bias[c + 1] + sk.y;
  float s1 = o0 + o1, s2 = o0 * o0 + o1 * o1;
#pragma unroll
  for (int of = 32; of; of >>= 1) {
    s1 += __shfl_xor(s1, of, 64);
    s2 += __shfl_xor(s2, of, 64);
  }
  float mu = s1 * (1.f / 128.f);
  float var = fmaxf(s2 * (1.f / 128.f) - mu * mu, 0.f);
  float rs = rsqrtf(var + 1e-5f);
  outp[(size_t)node * DOUT + c] = (o0 - mu) * rs * g[c] + be[c];
  outp[(size_t)node * DOUT + c + 1] = (o1 - mu) * rs * g[c + 1] + be[c + 1];
}

// ---------------- fallback kernels (r12): agg w/o LN, lnelu, ln128 ---------
__global__ __launch_bounds__(256) void l1_agg(
    const bf16* __restrict__ xl, const bf16* xr,
    const float* __restrict__ eatt, const float* __restrict__ We,
    const float* __restrict__ att, const float* __restrict__ bias,
    const int* __restrict__ srcs, const int* __restrict__ offs,
    const int* __restrict__ elist, bf16* hout) {
  int node = blockIdx.x;
  int tid = threadIdx.x;
  int w = tid >> 6, l = tid & 63;
  int c = w * 128 + 2 * l;
  f32x2 we[ED];
#pragma unroll
  for (int j = 0; j < ED; j++) {
    we[j] = (f32x2){We[(size_t)j * D1 + c], We[(size_t)j * D1 + c + 1]};
  }
  f32x2 av = ldf2v(att + c);
  f32x2 rv = ldbf2v(xr + (size_t)node * D1 + c);
  float m = -3.0e38f, den = 0.f;
  f32x2 acc = {0.f, 0.f};
  int i0 = offs[node], i1 = offs[node + 1];
  i0 = max(0, min(i0, EE));
  i1 = max(i0, min(i1, EE));
  int e = 0, s = 0;
  if (i0 < i1) {
    e = __builtin_amdgcn_readfirstlane(elist[i0]);
    s = __builtin_amdgcn_readfirstlane(srcs[e]);
  }
  for (int i = i0; i < i1; i++) {
    int e_n = e, s_n = s;
    if (i + 1 < i1) {
      e_n = __builtin_amdgcn_readfirstlane(elist[i + 1]);
      s_n = __builtin_amdgcn_readfirstlane(srcs[e_n]);
    }
    f32x2 xv = ldbf2v(xl + (size_t)s * D1 + c);
    const float* ear = eatt + (size_t)e * ED;
    f32x2 et = {0.f, 0.f};
#pragma unroll
    for (int j = 0; j < ED; j += 2) {
      f32x2 t = ldf2v(ear + j);
      et += (f32x2){t.x, t.x} * we[j];
      et += (f32x2){t.y, t.y} * we[j + 1];
    }
    f32x2 mm = xv + rv + et;
    f32x2 pos = {fmaxf(mm.x, 0.f), fmaxf(mm.y, 0.f)};
    f32x2 neg = {fminf(mm.x, 0.f), fminf(mm.y, 0.f)};
    mm = pos + 0.2f * neg;
    float al = mm.x * av.x + mm.y * av.y;
#pragma unroll
    for (int o = 32; o; o >>= 1) al += __shfl_xor(al, o, 64);
    float nm = fmaxf(m, al);
    float sc = __expf(m - nm);
    float pr = __expf(al - nm);
    den = den * sc + pr;
    acc = acc * sc + (f32x2){pr, pr} * xv;
    m = nm;
    e = e_n;
    s = s_n;
  }
  float inv = 1.f / (den + 1e-16f);
  hout[(size_t)node * D1 + c] = (bf16)(acc.x * inv + bias[c]);
  hout[(size_t)node * D1 + c + 1] = (bf16)(acc.y * inv + bias[c + 1]);
}

__global__ __launch_bounds__(256) void l2_agg(
    const float* __restrict__ xl, const float* xr,
    const float* __restrict__ eatt, const float* __restrict__ We,
    const float* __restrict__ att, const float* __restrict__ bias,
    const int* __restrict__ srcs, const int* __restrict__ offs,
    const int* __restrict__ elist, float* hout) {
  int tid = threadIdx.x;
  int w = tid >> 6, l = tid & 63;
  int node = blockIdx.x * 4 + w;
  if (node >= NN) return;
  int c = 2 * l;
  f32x2 we[ED];
#pragma unroll
  for (int j = 0; j < ED; j++) {
    we[j] = (f32x2){We[(size_t)j * DOUT + c], We[(size_t)j * DOUT + c + 1]};
  }
  f32x2 av = ldf2v(att + c);
  f32x2 rv = ldf2v(xr + (size_t)node * DOUT + c);
  float m = -3.0e38f, den = 0.f;
  f32x2 acc = {0.f, 0.f};
  int i0 = offs[node], i1 = offs[node + 1];
  i0 = max(0, min(i0, EE));
  i1 = max(i0, min(i1, EE));
  int e = 0, s = 0;
  if (i0 < i1) {
    e = __builtin_amdgcn_readfirstlane(elist[i0]);
    s = __builtin_amdgcn_readfirstlane(srcs[e]);
  }
  for (int i = i0; i < i1; i++) {
    int e_n = e, s_n = s;
    if (i + 1 < i1) {
      e_n = __builtin_amdgcn_readfirstlane(elist[i + 1]);
      s_n = __builtin_amdgcn_readfirstlane(srcs[e_n]);
    }
    f32x2 xv = ldf2v(xl + (size_t)s * DOUT + c);
    const float* ear = eatt + (size_t)e * ED;
    f32x2 et = {0.f, 0.f};
#pragma unroll
    for (int j = 0; j < ED; j += 2) {
      f32x2 t = ldf2v(ear + j);
      et += (f32x2){t.x, t.x} * we[j];
      et += (f32x2){t.y, t.y} * we[j + 1];
    }
    f32x2 mm = xv + rv + et;
    f32x2 pos = {fmaxf(mm.x, 0.f), fmaxf(mm.y, 0.f)};
    f32x2 neg = {fminf(mm.x, 0.f), fminf(mm.y, 0.f)};
    mm = pos + 0.2f * neg;
    float al = mm.x * av.x + mm.y * av.y;
#pragma unroll
    for (int o = 32; o; o >>= 1) al += __shfl_xor(al, o, 64);
    float nm = fmaxf(m, al);
    float sc = __expf(m - nm);
    float pr = __expf(al - nm);
    den = den * sc + pr;
    acc = acc * sc + (f32x2){pr, pr} * xv;
    m = nm;
    e = e_n;
    s = s_n;
  }
  float inv = 1.f / (den + 1e-16f);
  hout[(size_t)node * DOUT + c] = acc.x * inv + bias[c];
  hout[(size_t)node * DOUT + c + 1] = acc.y * inv + bias[c + 1];
}

__global__ __launch_bounds__(256) void lnelu_k(bf16* buf,
                                               const float* __restrict__ g,
                                               const float* __restrict__ be) {
  int node = blockIdx.x, tid = threadIdx.x;
  int w = tid >> 6, l = tid & 63;
  int c = tid * 2;
  f32x2 o = ldbf2v(buf + (size_t)node * D1 + c);
  float s1 = o.x + o.y, s2 = o.x * o.x + o.y * o.y;
#pragma unroll
  for (int of = 32; of; of >>= 1) {
    s1 += __shfl_xor(s1, of, 64);
    s2 += __shfl_xor(s2, of, 64);
  }
  __shared__ float r1[4], r2[4];
  if (l == 0) { r1[w] = s1; r2[w] = s2; }
  __syncthreads();
  float S1 = r1[0] + r1[1] + r1[2] + r1[3];
  float S2 = r2[0] + r2[1] + r2[2] + r2[3];
  float mu = S1 * (1.f / 512.f);
  float var = fmaxf(S2 * (1.f / 512.f) - mu * mu, 0.f);
  float rs = rsqrtf(var + 1e-5f);
  float y0 = (o.x - mu) * rs * g[c] + be[c];
  float y1 = (o.y - mu) * rs * g[c + 1] + be[c + 1];
  y0 = y0 > 0.f ? y0 : __expf(fminf(y0, 0.f)) - 1.f;
  y1 = y1 > 0.f ? y1 : __expf(fminf(y1, 0.f)) - 1.f;
  buf[(size_t)node * D1 + c] = (bf16)y0;
  buf[(size_t)node * D1 + c + 1] = (bf16)y1;
}

__global__ __launch_bounds__(256) void ln128_k(const float* __restrict__ buf,
                                               const float* __restrict__ g,
                                               const float* __restrict__ be,
                                               float* __restrict__ outp) {
  int tid = threadIdx.x;
  int w = tid >> 6, l = tid & 63;
  int node = blockIdx.x * 4 + w;
  if (node >= NN) return;
  int c = 2 * l;
  f32x2 o = ldf2v(buf + (size_t)node * DOUT + c);
  float s1 = o.x + o.y, s2 = o.x * o.x + o.y * o.y;
#pragma unroll
  for (int of = 32; of; of >>= 1) {
    s1 += __shfl_xor(s1, of, 64);
    s2 += __shfl_xor(s2, of, 64);
  }
  float mu = s1 * (1.f / 128.f);
  float var = fmaxf(s2 * (1.f / 128.f) - mu * mu, 0.f);
  float rs = rsqrtf(var + 1e-5f);
  outp[(size_t)node * DOUT + c] = (o.x - mu) * rs * g[c] + be[c];
  outp[(size_t)node * DOUT + c + 1] = (o.y - mu) * rs * g[c + 1] + be[c + 1];
}

extern "C" void kernel_launch(void* const* d_in, const int* in_sizes, int n_in,
                              void* d_out, int out_size, void* d_ws, size_t ws_size,
                              hipStream_t stream) {
  const float* x = (const float*)d_in[0];
  const void* ei = d_in[1];
  const float* eattr = (const float*)d_in[2];
  const float* W1l = (const float*)d_in[3];
  const float* b1l = (const float*)d_in[4];
  const float* W1r = (const float*)d_in[5];
  const float* b1r = (const float*)d_in[6];
  const float* We1 = (const float*)d_in[7];
  const float* att1 = (const float*)d_in[8];
  const float* bias1 = (const float*)d_in[9];
  const float* Wsk1 = (const float*)d_in[10];
  const float* bsk1 = (const float*)d_in[11];
  const float* g1 = (const float*)d_in[12];
  const float* be1 = (const float*)d_in[13];
  const float* W2l = (const float*)d_in[14];
  const float* b2l = (const float*)d_in[15];
  const float* W2r = (const float*)d_in[16];
  const float* b2r = (const float*)d_in[17];
  const float* We2 = (const float*)d_in[18];
  const float* att2 = (const float*)d_in[19];
  const float* bias2 = (const float*)d_in[20];
  const float* Wsk2 = (const float*)d_in[21];
  const float* bsk2 = (const float*)d_in[22];
  const float* g2 = (const float*)d_in[23];
  const float* be2 = (const float*)d_in[24];

  // workspace carve (256B aligned)
  char* p = (char*)d_ws;
  size_t off = 0;
  auto carve = [&](size_t bytes) {
    void* r = p + off;
    off = (off + bytes + 255) & ~(size_t)255;
    return r;
  };
  int* flag = (int*)carve(sizeof(int));
  int* srcD = (int*)carve(EE * sizeof(int));
  int* dstD = (int*)carve(EE * sizeof(int));
  int* deg = (int*)carve(NN * sizeof(int));
  int* offs = (int*)carve((NN + 1) * sizeof(int));
  int* cursor = (int*)carve(NN * sizeof(int));
  int* elist = (int*)carve(EE * sizeof(int));
  bf16* bufA = (bf16*)carve((size_t)NN * D1 * 2);  // xl1; then f32 x2l/x2r
  bf16* bufB = (bf16*)carve((size_t)NN * D1 * 2);  // xr1 -> h -> alpha2 scratch
  size_t base_need = off;
  bf16* bufC = (bf16*)carve((size_t)NN * D1 * 2);  // skip1 bf16 / skip2 f32
  bool fused = (off <= ws_size);
  // tier-2 extras: CSR-gathered edge data
  bf16* eacsr = (bf16*)carve((size_t)EE * 32 * 2);  // [E][32] bf16, K-pad 0
  int* s_csr = (int*)carve(EE * sizeof(int));
  int* d_csr = (int*)carve(EE * sizeof(int));
  bool fused2 = (off <= ws_size);
  // tier-3: x pre-packed to bf16 (layer-1 GEMM A fast path)
  bf16* xbf = (bf16*)carve((size_t)NN * FIN * 2);
  bool fused3 = (off <= ws_size);

  float* q0 = (float*)bufA;              // x2l (f32)
  float* q1 = q0 + (size_t)NN * DOUT;    // x2r (f32)
  float* sk2 = (float*)bufC;             // skip2 (f32, fused path)
  float* alph1 = (float*)d_out;          // [E,4] logits
  float* alph2 = (float*)bufB;           // [E] logits
  // d_out tail (agg2 rewrites all of d_out at the very end):
  bf16* W1p = (bf16*)((char*)d_out + 5120000);   // 3 x 512x256 bf16
  bf16* W2p = W1p + (size_t)3 * D1 * FIN;        // 3 x 128x512 bf16
  bf16* Wep1 = W2p + (size_t)3 * DOUT * D1;      // 16384 bf16 (32 KB)
  bf16* Wep2 = Wep1 + 16384;                     // 4096 bf16 (8 KB)

  // edge_index detect + convert
  zero_k<<<1, 256, 0, stream>>>(flag, 1);
  detflag_k<<<(EE + 255) / 256, 256, 0, stream>>>((const int*)ei, flag);
  conv_k<<<(EE + 255) / 256, 256, 0, stream>>>(ei, flag, srcD, dstD);

  // CSR build (by dst)
  zero_k<<<(NN + 255) / 256, 256, 0, stream>>>(deg, NN);
  hist_k<<<(EE + 255) / 256, 256, 0, stream>>>(dstD, deg, EE);
  scan_k<<<1, 1024, 0, stream>>>(deg, offs, cursor, NN);
  scatter_k<<<(EE + 255) / 256, 256, 0, stream>>>(dstD, cursor, elist, EE);

  if (fused) {
    // pack weights: W[K][Nc] f32 -> Wp[mat][col][k] bf16
    packT_k<<<dim3(D1 / 32, FIN / 32), 256, 0, stream>>>(W1l, W1p, D1, FIN);
    packT_k<<<dim3(D1 / 32, FIN / 32), 256, 0, stream>>>(
        W1r, W1p + (size_t)D1 * FIN, D1, FIN);
    packT_k<<<dim3(D1 / 32, FIN / 32), 256, 0, stream>>>(
        Wsk1, W1p + (size_t)2 * D1 * FIN, D1, FIN);
    packT_k<<<dim3(DOUT / 32, D1 / 32), 256, 0, stream>>>(W2l, W2p, DOUT, D1);
    packT_k<<<dim3(DOUT / 32, D1 / 32), 256, 0, stream>>>(
        W2r, W2p + (size_t)DOUT * D1, DOUT, D1);
    packT_k<<<dim3(DOUT / 32, D1 / 32), 256, 0, stream>>>(
        Wsk2, W2p + (size_t)2 * DOUT * D1, DOUT, D1);
    // pack We into MFMA fragment order (for tier-2 alpha kernels)
    packWe_k<<<64, 256, 0, stream>>>(We1, Wep1, D1);
    packWe_k<<<16, 256, 0, stream>>>(We2, Wep2, DOUT);
    // layer-1 GEMM (bf16-A fast path when tier-3 workspace fits)
    if (fused3) {
      const long long n8 = (long long)NN * FIN / 8;  // 640000
      xpack_k<<<(unsigned)((n8 + 255) / 256), 256, 0, stream>>>(x, xbf, n8);
      gemm3p_t<bf16, bf16><<<dim3(D1 / 64, (NN + 63) / 64), 256, 0, stream>>>(
          xbf, W1p, b1l, b1r, bsk1, bufA, bufB, bufC, D1, FIN, NN);
    } else {
      gemm3p_t<float, bf16><<<dim3(D1 / 64, (NN + 63) / 64), 256, 0, stream>>>(
          x, W1p, b1l, b1r, bsk1, bufA, bufB, bufC, D1, FIN, NN);
    }
    if (fused2) {
      egather_k<<<EE / 128, 256, 0, stream>>>(eattr, elist, srcD, dstD,
                                              eacsr, s_csr, d_csr);
      alpha1c_k<<<EE / 128, 256, 0, stream>>>(bufA, bufB, eacsr, Wep1, att1,
                                              s_csr, d_csr, alph1);
      agg1c_k<<<(NN + 3) / 4, 256, 0, stream>>>(bufA, bufC, alph1, bias1, g1,
                                                be1, s_csr, offs, bufB);
      gemm3p_t<bf16, float><<<dim3(DOUT / 64, (NN + 63) / 64), 256, 0, stream>>>(
          bufB, W2p, b2l, b2r, bsk2, q0, q1, sk2, DOUT, D1, NN);
      alpha2c_k<<<EE / 128, 256, 0, stream>>>(q0, q1, eacsr, Wep2, att2,
                                              s_csr, d_csr, alph2);
      agg2c_k<<<(NN + 3) / 4, 256, 0, stream>>>(q0, sk2, alph2, bias2, g2, be2,
                                                s_csr, offs, (float*)d_out);
    } else {
      alpha1_k<<<EE / 128, 256, 0, stream>>>(bufA, bufB, eattr, We1, att1,
                                             srcD, dstD, alph1);
      agg1_k<<<(NN + 3) / 4, 256, 0, stream>>>(bufA, bufC, alph1, bias1, g1,
                                               be1, srcD, offs, elist, bufB);
      gemm3p_t<bf16, float><<<dim3(DOUT / 64, (NN + 63) / 64), 256, 0, stream>>>(
          bufB, W2p, b2l, b2r, bsk2, q0, q1, sk2, DOUT, D1, NN);
      alpha2_k<<<EE / 128, 256, 0, stream>>>(q0, q1, eattr, We2, att2,
                                             srcD, dstD, alph2);
      agg2_k<<<(NN + 3) / 4, 256, 0, stream>>>(q0, sk2, alph2, bias2, g2, be2,
                                               srcD, offs, elist, (float*)d_out);
    }
  } else {
    // r12 fallback path (fits in base_need bytes)
    (void)base_need;
    gemm2_t<float, bf16><<<dim3(D1 / 64, NN / 16), 256, 0, stream>>>(
        x, W1l, W1r, b1l, b1r, bufA, bufB, D1, FIN);
    l1_agg<<<NN, 256, 0, stream>>>(bufA, bufB, eattr, We1, att1, bias1,
                                   srcD, offs, elist, bufB);
    gemm_t<float, bf16, true><<<dim3(D1 / 64, NN / 16), 256, 0, stream>>>(
        x, Wsk1, bsk1, bufB, D1, FIN);
    lnelu_k<<<NN, 256, 0, stream>>>(bufB, g1, be1);
    gemm2_t<bf16, float><<<dim3(DOUT / 64, NN / 16), 256, 0, stream>>>(
        bufB, W2l, W2r, b2l, b2r, q0, q1, DOUT, D1);
    l2_agg<<<(NN + 3) / 4, 256, 0, stream>>>(q0, q1, eattr, We2, att2, bias2,
                                             srcD, offs, elist, q1);
    gemm_t<bf16, float, true><<<dim3(DOUT / 64, NN / 16), 256, 0, stream>>>(
        bufB, Wsk2, bsk2, q1, DOUT, D1);
    ln128_k<<<(NN + 3) / 4, 256, 0, stream>>>(q1, g2, be2, (float*)d_out);
  }

  (void)in_sizes; (void)n_in; (void)out_size;
}

// Round 11
// 594.367 us; speedup vs baseline: 1.1247x; 1.0525x over previous
//
#include <hip/hip_runtime.h>
#include <hip/hip_bf16.h>

typedef __bf16 bf16;
typedef __bf16 v8bf __attribute__((ext_vector_type(8)));
typedef float f32x4 __attribute__((ext_vector_type(4)));
typedef float f32x2 __attribute__((ext_vector_type(2)));

#define NN 20000
#define EE 320000
#define FIN 256
#define D1 512
#define DOUT 128
#define ED 26

__device__ __forceinline__ float b2f(bf16 x) { return (float)x; }

__device__ __forceinline__ f32x2 ldbf2v(const bf16* p) {
  unsigned int u;
  __builtin_memcpy(&u, p, 4);
  union { unsigned int i; float f; } lo, hi;
  lo.i = (u & 0xffffu) << 16;
  hi.i = u & 0xffff0000u;
  return (f32x2){lo.f, hi.f};
}

__device__ __forceinline__ f32x2 ldf2v(const float* p) {
  f32x2 t;
  __builtin_memcpy(&t, p, 8);
  return t;
}

__device__ __forceinline__ f32x4 ldf4v(const float* p) {
  f32x4 t;
  __builtin_memcpy(&t, p, 16);
  return t;
}

// ---------------- small utils ----------------
__global__ void zero_k(int* __restrict__ p, int n) {
  int i = blockIdx.x * 256 + threadIdx.x;
  if (i < n) p[i] = 0;
}

__global__ void zero2_k(int* __restrict__ deg, int* __restrict__ flag) {
  int i = blockIdx.x * 256 + threadIdx.x;
  if (i < NN) deg[i] = 0;
  if (i == 0) *flag = 0;
}

// ---------------- edge_index dtype detect + convert ------------------------
__global__ void detflag_k(const int* __restrict__ ei32, int* __restrict__ flag) {
  int i = blockIdx.x * 256 + threadIdx.x;
  int v = (i < EE) ? ei32[2 * i + 1] : 0;
  unsigned long long b = __ballot(v != 0);
  if ((threadIdx.x & 63) == 0 && b) atomicOr(flag, 1);
}

__global__ void conv_k(const void* __restrict__ ei, const int* __restrict__ flag,
                       int* __restrict__ src, int* __restrict__ dst) {
  int i = blockIdx.x * 256 + threadIdx.x;
  if (i >= EE) return;
  int s, d;
  if (*flag == 0) {
    const long long* p = (const long long*)ei;
    s = (int)p[i];
    d = (int)p[EE + i];
  } else {
    const int* p = (const int*)ei;
    s = p[i];
    d = p[EE + i];
  }
  src[i] = min(max(s, 0), NN - 1);
  dst[i] = min(max(d, 0), NN - 1);
}

// conv + degree histogram fused
__global__ void conv_hist_k(const void* __restrict__ ei,
                            const int* __restrict__ flag, int* __restrict__ src,
                            int* __restrict__ dst, int* __restrict__ deg) {
  int i = blockIdx.x * 256 + threadIdx.x;
  if (i >= EE) return;
  int s, d;
  if (*flag == 0) {
    const long long* p = (const long long*)ei;
    s = (int)p[i];
    d = (int)p[EE + i];
  } else {
    const int* p = (const int*)ei;
    s = p[i];
    d = p[EE + i];
  }
  s = min(max(s, 0), NN - 1);
  d = min(max(d, 0), NN - 1);
  src[i] = s;
  dst[i] = d;
  atomicAdd(&deg[d], 1);
}

// ---------------- CSR build ----------------
__global__ void hist_k(const int* __restrict__ dst, int* __restrict__ deg, int n) {
  int e = blockIdx.x * 256 + threadIdx.x;
  if (e < n) atomicAdd(&deg[dst[e]], 1);
}

__global__ __launch_bounds__(1024) void scan_k(const int* __restrict__ deg,
                                               int* __restrict__ offs,
                                               int* __restrict__ cursor, int n) {
  __shared__ int lsum[1024];
  int t = threadIdx.x;
  const int CH = (n + 1023) / 1024;
  int base = t * CH;
  int s = 0;
  for (int i = 0; i < CH; i++) {
    int idx = base + i;
    if (idx < n) s += deg[idx];
  }
  lsum[t] = s;
  __syncthreads();
  for (int o = 1; o < 1024; o <<= 1) {
    int v = (t >= o) ? lsum[t - o] : 0;
    __syncthreads();
    lsum[t] += v;
    __syncthreads();
  }
  int ex = (t == 0) ? 0 : lsum[t - 1];
  for (int i = 0; i < CH; i++) {
    int idx = base + i;
    if (idx < n) {
      offs[idx] = ex;
      cursor[idx] = ex;
      ex += deg[idx];
    }
  }
  if (t == 1023) offs[n] = lsum[1023];
}

__global__ void scatter_k(const int* __restrict__ dst, int* __restrict__ cursor,
                          int* __restrict__ elist, int n) {
  int e = blockIdx.x * 256 + threadIdx.x;
  if (e < n) {
    int p = atomicAdd(&cursor[dst[e]], 1);
    if ((unsigned)p < (unsigned)EE) elist[p] = e;
  }
}

// ------- fused scatter + CSR-gather: contiguous eatt READ, scattered WRITE -
__global__ __launch_bounds__(256) void scatter_eg_k(
    const float* __restrict__ eattr, const int* __restrict__ srcs,
    const int* __restrict__ dsts, int* __restrict__ cursor,
    int* __restrict__ elist, bf16* __restrict__ ea_csr,
    int* __restrict__ s_csr, int* __restrict__ d_csr) {
  int e = blockIdx.x * 256 + threadIdx.x;
  if (e >= EE) return;
  int s = srcs[e], d = dsts[e];
  int p = atomicAdd(&cursor[d], 1);
  if ((unsigned)p >= (unsigned)EE) return;
  elist[p] = e;
  s_csr[p] = s;
  d_csr[p] = d;
  const float* er = eattr + (size_t)e * ED;
  bf16 row[32];
#pragma unroll
  for (int k = 0; k < 26; k++) row[k] = (bf16)er[k];
#pragma unroll
  for (int k = 26; k < 32; k++) row[k] = (bf16)0.f;
  __builtin_memcpy(ea_csr + (size_t)p * 32, row, 64);
}

// ------- ALL packing in one launch: 6x packT + 2x packWe + xpack -----------
// blocks [0,384): W1l/W1r/Wsk1 (Nc=512,K=256, 128 blocks each)
// blocks [384,576): W2l/W2r/Wsk2 (Nc=128,K=512, 64 blocks each)
// blocks [576,640): packWe1; [640,656): packWe2; [656,3156): xpack
__global__ __launch_bounds__(256) void packall_k(
    const float* __restrict__ W1l, const float* __restrict__ W1r,
    const float* __restrict__ Wsk1, const float* __restrict__ W2l,
    const float* __restrict__ W2r, const float* __restrict__ Wsk2,
    const float* __restrict__ We1, const float* __restrict__ We2,
    const float* __restrict__ x, bf16* __restrict__ W1p,
    bf16* __restrict__ W2p, bf16* __restrict__ Wep1, bf16* __restrict__ Wep2,
    bf16* __restrict__ xbf) {
  __shared__ float t[32][33];
  int b = blockIdx.x;
  int tid = threadIdx.x;
  if (b < 576) {
    const float* W;
    bf16* Bp;
    int Nc, K, bx, by;
    if (b < 384) {
      int j = b / 128, tt = b % 128;
      W = j == 0 ? W1l : (j == 1 ? W1r : Wsk1);
      Bp = W1p + (size_t)j * D1 * FIN;
      Nc = D1;
      K = FIN;
      bx = tt % 16;
      by = tt / 16;
    } else {
      int j = (b - 384) / 64, tt = (b - 384) % 64;
      W = j == 0 ? W2l : (j == 1 ? W2r : Wsk2);
      Bp = W2p + (size_t)j * DOUT * D1;
      Nc = DOUT;
      K = D1;
      bx = tt % 4;
      by = tt / 4;
    }
    int c0 = bx * 32, k0 = by * 32;
    int tr = tid >> 5, tc = tid & 31;
#pragma unroll
    for (int i = 0; i < 32; i += 8)
      t[tr + i][tc] = W[(size_t)(k0 + tr + i) * Nc + c0 + tc];
    __syncthreads();
#pragma unroll
    for (int i = 0; i < 32; i += 8)
      Bp[(size_t)(c0 + tr + i) * K + k0 + tc] = (bf16)t[tc][tr + i];
  } else if (b < 656) {
    const float* We;
    bf16* Wp;
    int Nc, blk;
    if (b < 640) {
      We = We1; Wp = Wep1; Nc = D1; blk = b - 576;
    } else {
      We = We2; Wp = Wep2; Nc = DOUT; blk = b - 640;
    }
    int o = blk * 256 + tid;
    int j = o & 7, lc = (o >> 3) & 15, quad = (o >> 7) & 3, ng = o >> 9;
    int k = quad * 8 + j, col = ng * 16 + lc;
    float v = (k < 26) ? We[(size_t)k * Nc + col] : 0.f;
    Wp[o] = (bf16)v;
  } else {
    long long i = (long long)(b - 656) * 256 + tid;  // exactly 640000 total
    const float* ap = x + i * 8;
    f32x4 u, v;
    __builtin_memcpy(&u, ap, 16);
    __builtin_memcpy(&v, ap + 4, 16);
    v8bf o;
#pragma unroll
    for (int j = 0; j < 4; j++) {
      o[j] = (bf16)u[j];
      o[4 + j] = (bf16)v[j];
    }
    __builtin_memcpy(xbf + i * 8, &o, 16);
  }
}

// ------- MFMA GEMM (single-output, for fallback skip ADD) ------------------
template <typename TA, typename TO, bool ADD>
__global__ __launch_bounds__(256) void gemm_t(const TA* __restrict__ A,
                                              const float* __restrict__ B,
                                              const float* __restrict__ bias,
                                              TO* out, int Nc, int K) {
  int w = threadIdx.x >> 6;
  int l = threadIdx.x & 63;
  int quad = l >> 4;
  int mrow = blockIdx.y * 16 + (l & 15);
  int col = blockIdx.x * 64 + w * 16 + (l & 15);
  f32x4 acc = {0.f, 0.f, 0.f, 0.f};
  for (int k0 = 0; k0 < K; k0 += 32) {
    int ka = k0 + quad * 8;
    v8bf a, b;
    if constexpr (sizeof(TA) == 4) {
      const float* ap = (const float*)A + (size_t)mrow * K + ka;
#pragma unroll
      for (int j = 0; j < 8; j++) a[j] = (bf16)ap[j];
    } else {
      __builtin_memcpy(&a, (const bf16*)A + (size_t)mrow * K + ka, 16);
    }
#pragma unroll
    for (int j = 0; j < 8; j++) b[j] = (bf16)B[(size_t)(ka + j) * Nc + col];
    acc = __builtin_amdgcn_mfma_f32_16x16x32_bf16(a, b, acc, 0, 0, 0);
  }
  float bb = bias[col];
  int obase = blockIdx.y * 16 + quad * 4;
#pragma unroll
  for (int r = 0; r < 4; r++) {
    size_t idx = (size_t)(obase + r) * Nc + col;
    float v = acc[r] + bb;
    if (ADD) v += (float)out[idx];
    out[idx] = (TO)v;
  }
}

// ------- 2-output fused MFMA GEMM (fallback path) --------------------------
template <typename TA, typename TO>
__global__ __launch_bounds__(256) void gemm2_t(const TA* __restrict__ A,
                                               const float* __restrict__ B0,
                                               const float* __restrict__ B1,
                                               const float* __restrict__ bias0,
                                               const float* __restrict__ bias1,
                                               TO* __restrict__ out0,
                                               TO* __restrict__ out1,
                                               int Nc, int K) {
  int w = threadIdx.x >> 6;
  int l = threadIdx.x & 63;
  int quad = l >> 4;
  int mrow = blockIdx.y * 16 + (l & 15);
  int col = blockIdx.x * 64 + w * 16 + (l & 15);
  f32x4 acc0 = {0.f, 0.f, 0.f, 0.f};
  f32x4 acc1 = {0.f, 0.f, 0.f, 0.f};
  for (int k0 = 0; k0 < K; k0 += 32) {
    int ka = k0 + quad * 8;
    v8bf a, b0, b1;
    if constexpr (sizeof(TA) == 4) {
      const float* ap = (const float*)A + (size_t)mrow * K + ka;
#pragma unroll
      for (int j = 0; j < 8; j++) a[j] = (bf16)ap[j];
    } else {
      __builtin_memcpy(&a, (const bf16*)A + (size_t)mrow * K + ka, 16);
    }
#pragma unroll
    for (int j = 0; j < 8; j++) {
      size_t bi = (size_t)(ka + j) * Nc + col;
      b0[j] = (bf16)B0[bi];
      b1[j] = (bf16)B1[bi];
    }
    acc0 = __builtin_amdgcn_mfma_f32_16x16x32_bf16(a, b0, acc0, 0, 0, 0);
    acc1 = __builtin_amdgcn_mfma_f32_16x16x32_bf16(a, b1, acc1, 0, 0, 0);
  }
  float bb0 = bias0[col], bb1 = bias1[col];
  int obase = blockIdx.y * 16 + quad * 4;
#pragma unroll
  for (int r = 0; r < 4; r++) {
    size_t idx = (size_t)(obase + r) * Nc + col;
    out0[idx] = (TO)(acc0[r] + bb0);
    out1[idx] = (TO)(acc1[r] + bb1);
  }
}

// ------- 3-output packed-B MFMA GEMM: 64x64 tile, 4 M-subtiles/wave --------
template <typename TA, typename TO>
__global__ __launch_bounds__(256) void gemm3p_t(
    const TA* __restrict__ A, const bf16* __restrict__ Bp,
    const float* __restrict__ bias0, const float* __restrict__ bias1,
    const float* __restrict__ bias2, TO* __restrict__ out0,
    TO* __restrict__ out1, TO* __restrict__ out2, int Nc, int K, int M) {
  int w = threadIdx.x >> 6;
  int l = threadIdx.x & 63;
  int quad = l >> 4, lc = l & 15;
  int col = blockIdx.x * 64 + w * 16 + lc;
  int mbase = blockIdx.y * 64;
  const bf16* b0p = Bp + (size_t)col * K;
  const bf16* b1p = Bp + ((size_t)Nc + col) * K;
  const bf16* b2p = Bp + ((size_t)2 * Nc + col) * K;
  f32x4 acc[4][3];
#pragma unroll
  for (int i = 0; i < 4; i++)
#pragma unroll
    for (int j = 0; j < 3; j++) acc[i][j] = (f32x4){0.f, 0.f, 0.f, 0.f};
  for (int k0 = 0; k0 < K; k0 += 32) {
    int ka = k0 + quad * 8;
    v8bf b0, b1, b2;
    __builtin_memcpy(&b0, b0p + ka, 16);
    __builtin_memcpy(&b1, b1p + ka, 16);
    __builtin_memcpy(&b2, b2p + ka, 16);
#pragma unroll
    for (int ms = 0; ms < 4; ms++) {
      int row = min(mbase + ms * 16 + lc, M - 1);
      v8bf a;
      if constexpr (sizeof(TA) == 4) {
        const float* ap = (const float*)A + (size_t)row * K + ka;
        f32x4 u, v;
        __builtin_memcpy(&u, ap, 16);
        __builtin_memcpy(&v, ap + 4, 16);
#pragma unroll
        for (int j = 0; j < 4; j++) {
          a[j] = (bf16)u[j];
          a[4 + j] = (bf16)v[j];
        }
      } else {
        __builtin_memcpy(&a, (const bf16*)A + (size_t)row * K + ka, 16);
      }
      acc[ms][0] = __builtin_amdgcn_mfma_f32_16x16x32_bf16(a, b0, acc[ms][0], 0, 0, 0);
      acc[ms][1] = __builtin_amdgcn_mfma_f32_16x16x32_bf16(a, b1, acc[ms][1], 0, 0, 0);
      acc[ms][2] = __builtin_amdgcn_mfma_f32_16x16x32_bf16(a, b2, acc[ms][2], 0, 0, 0);
    }
  }
  float bb0 = bias0[col], bb1 = bias1[col], bb2 = bias2[col];
#pragma unroll
  for (int ms = 0; ms < 4; ms++) {
    int ob = mbase + ms * 16 + quad * 4;
#pragma unroll
    for (int r = 0; r < 4; r++) {
      int orow = ob + r;
      if (orow < M) {
        size_t idx = (size_t)orow * Nc + col;
        out0[idx] = (TO)(acc[ms][0][r] + bb0);
        out1[idx] = (TO)(acc[ms][1][r] + bb1);
        out2[idx] = (TO)(acc[ms][2][r] + bb2);
      }
    }
  }
}

// ==== TIER-2: CSR-order MFMA alpha (R10-measured-best form) ================
__global__ __launch_bounds__(256) void alpha1c_k(
    const bf16* __restrict__ xl, const bf16* __restrict__ xr,
    const bf16* __restrict__ ea_csr, const bf16* __restrict__ Wp,
    const float* __restrict__ att, const int* __restrict__ s_csr,
    const int* __restrict__ d_csr, float* __restrict__ alphap) {
  __shared__ bf16 ea_s[128 * 40];
  int tid = threadIdx.x;
  int w = __builtin_amdgcn_readfirstlane(tid >> 6);
  int l = tid & 63;
  int quad = l >> 4, lc = l & 15;
  int base = blockIdx.x * 128;
  for (int idx = tid; idx < 1024; idx += 256) {
    int i = idx >> 3, k4 = (idx & 7) * 4;
    unsigned long long v;
    __builtin_memcpy(&v, ea_csr + (size_t)(base + i) * 32 + k4, 8);
    __builtin_memcpy(&ea_s[i * 40 + k4], &v, 8);
  }
  int c0 = w * 128;
  v8bf bfrag[8];
  float av[8];
#pragma unroll
  for (int n = 0; n < 8; n++) {
    int col = c0 + n * 16 + lc;
    av[n] = att[col];
    __builtin_memcpy(&bfrag[n],
                     Wp + ((size_t)((w * 8 + n) * 4 + quad) * 16 + lc) * 8, 16);
  }
  __syncthreads();
#pragma unroll 1
  for (int m = 0; m < 8; m++) {
    v8bf afrag;
    __builtin_memcpy(&afrag, &ea_s[(m * 16 + lc) * 40 + quad * 8], 16);
    f32x4 z = {0.f, 0.f, 0.f, 0.f};
    f32x4 acc[8];
#pragma unroll
    for (int n = 0; n < 8; n++)
      acc[n] = __builtin_amdgcn_mfma_f32_16x16x32_bf16(afrag, bfrag[n], z, 0, 0, 0);
    int e0 = base + m * 16 + quad * 4;
    int sA[4], dA[4];
#pragma unroll
    for (int r = 0; r < 4; r++) {
      sA[r] = s_csr[e0 + r];
      dA[r] = d_csr[e0 + r];
    }
    f32x4 pal = {0.f, 0.f, 0.f, 0.f};
#pragma unroll
    for (int n = 0; n < 8; n++) {
      int col = c0 + n * 16 + lc;
#pragma unroll
      for (int r = 0; r < 4; r++) {
        float mm = (float)xl[(size_t)sA[r] * D1 + col] +
                   (float)xr[(size_t)dA[r] * D1 + col] + acc[n][r];
        mm = fmaxf(mm, 0.f) + 0.2f * fminf(mm, 0.f);
        pal[r] += mm * av[n];
      }
    }
#pragma unroll
    for (int o = 1; o < 16; o <<= 1) {
      pal[0] += __shfl_xor(pal[0], o, 64);
      pal[1] += __shfl_xor(pal[1], o, 64);
      pal[2] += __shfl_xor(pal[2], o, 64);
      pal[3] += __shfl_xor(pal[3], o, 64);
    }
    if (lc == 0) {
#pragma unroll
      for (int r = 0; r < 4; r++) alphap[(size_t)(e0 + r) * 4 + w] = pal[r];
    }
  }
}

__global__ __launch_bounds__(256) void alpha2c_k(
    const float* __restrict__ xl, const float* __restrict__ xr,
    const bf16* __restrict__ ea_csr, const bf16* __restrict__ Wp,
    const float* __restrict__ att, const int* __restrict__ s_csr,
    const int* __restrict__ d_csr, float* __restrict__ alphap) {
  __shared__ bf16 ea_s[128 * 40];
  __shared__ float pal_s[4 * 128];
  int tid = threadIdx.x;
  int w = __builtin_amdgcn_readfirstlane(tid >> 6);
  int l = tid & 63;
  int quad = l >> 4, lc = l & 15;
  int base = blockIdx.x * 128;
  for (int idx = tid; idx < 1024; idx += 256) {
    int i = idx >> 3, k4 = (idx & 7) * 4;
    unsigned long long v;
    __builtin_memcpy(&v, ea_csr + (size_t)(base + i) * 32 + k4, 8);
    __builtin_memcpy(&ea_s[i * 40 + k4], &v, 8);
  }
  int c0 = w * 32;
  v8bf bfrag[2];
  float av[2];
#pragma unroll
  for (int n = 0; n < 2; n++) {
    int col = c0 + n * 16 + lc;
    av[n] = att[col];
    __builtin_memcpy(&bfrag[n],
                     Wp + ((size_t)((w * 2 + n) * 4 + quad) * 16 + lc) * 8, 16);
  }
  __syncthreads();
#pragma unroll 1
  for (int m = 0; m < 8; m++) {
    v8bf afrag;
    __builtin_memcpy(&afrag, &ea_s[(m * 16 + lc) * 40 + quad * 8], 16);
    f32x4 z = {0.f, 0.f, 0.f, 0.f};
    f32x4 acc[2];
#pragma unroll
    for (int n = 0; n < 2; n++)
      acc[n] = __builtin_amdgcn_mfma_f32_16x16x32_bf16(afrag, bfrag[n], z, 0, 0, 0);
    int e0 = base + m * 16 + quad * 4;
    int sA[4], dA[4];
#pragma unroll
    for (int r = 0; r < 4; r++) {
      sA[r] = s_csr[e0 + r];
      dA[r] = d_csr[e0 + r];
    }
    f32x4 pal = {0.f, 0.f, 0.f, 0.f};
#pragma unroll
    for (int n = 0; n < 2; n++) {
      int col = c0 + n * 16 + lc;
#pragma unroll
      for (int r = 0; r < 4; r++) {
        float mm = xl[(size_t)sA[r] * DOUT + col] +
                   xr[(size_t)dA[r] * DOUT + col] + acc[n][r];
        mm = fmaxf(mm, 0.f) + 0.2f * fminf(mm, 0.f);
        pal[r] += mm * av[n];
      }
    }
#pragma unroll
    for (int o = 1; o < 16; o <<= 1) {
      pal[0] += __shfl_xor(pal[0], o, 64);
      pal[1] += __shfl_xor(pal[1], o, 64);
      pal[2] += __shfl_xor(pal[2], o, 64);
      pal[3] += __shfl_xor(pal[3], o, 64);
    }
    if (lc == 0) {
      int eb = m * 16 + quad * 4;
#pragma unroll
      for (int r = 0; r < 4; r++) pal_s[w * 128 + eb + r] = pal[r];
    }
  }
  __syncthreads();
  if (tid < 128) {
    float a = pal_s[tid] + pal_s[128 + tid] + pal_s[256 + tid] + pal_s[384 + tid];
    alphap[base + tid] = a;
  }
}

// ==== TIER-2 aggs: wave-per-node, contiguous alpha/s reads, lane-par max ===
__global__ __launch_bounds__(256) void agg1c_k(
    const bf16* __restrict__ xl, const bf16* __restrict__ skip,
    const float* __restrict__ alphap, const float* __restrict__ bias,
    const float* __restrict__ g, const float* __restrict__ be,
    const int* __restrict__ s_csr, const int* __restrict__ offs,
    bf16* __restrict__ hout) {
  int tid = threadIdx.x;
  int w = tid >> 6, l = tid & 63;
  int node = blockIdx.x * 4 + w;
  if (node >= NN) return;
  int c = l * 8;
  int head = l >> 4;
  int i0 = offs[node], i1 = offs[node + 1];
  i0 = max(0, min(i0, EE));
  i1 = max(i0, min(i1, EE));
  float m = -3.0e38f;
  for (int i = i0 + (l & 15); i < i1; i += 16)
    m = fmaxf(m, alphap[(size_t)i * 4 + head]);
#pragma unroll
  for (int o = 1; o < 16; o <<= 1) m = fmaxf(m, __shfl_xor(m, o, 64));
  float den = 0.f;
  f32x4 a0 = {0.f, 0.f, 0.f, 0.f}, a1 = {0.f, 0.f, 0.f, 0.f};
  int s = 0;
  float al = 0.f;
  if (i0 < i1) {
    s = __builtin_amdgcn_readfirstlane(s_csr[i0]);
    al = alphap[(size_t)i0 * 4 + head];
  }
  for (int i = i0; i < i1; i++) {
    int s_n = s;
    float al_n = al;
    if (i + 1 < i1) {
      s_n = __builtin_amdgcn_readfirstlane(s_csr[i + 1]);
      al_n = alphap[(size_t)(i + 1) * 4 + head];
    }
    float pr = __expf(al - m);
    den += pr;
    v8bf xv;
    __builtin_memcpy(&xv, xl + (size_t)s * D1 + c, 16);
#pragma unroll
    for (int j = 0; j < 4; j++) {
      a0[j] += pr * (float)xv[j];
      a1[j] += pr * (float)xv[4 + j];
    }
    s = s_n;
    al = al_n;
  }
  float inv = 1.f / (den + 1e-16f);
  v8bf skv;
  __builtin_memcpy(&skv, skip + (size_t)node * D1 + c, 16);
  f32x4 bv0 = ldf4v(bias + c), bv1 = ldf4v(bias + c + 4);
  float o[8];
#pragma unroll
  for (int j = 0; j < 4; j++) {
    o[j] = a0[j] * inv + bv0[j] + (float)skv[j];
    o[4 + j] = a1[j] * inv + bv1[j] + (float)skv[4 + j];
  }
  float s1 = 0.f, s2 = 0.f;
#pragma unroll
  for (int j = 0; j < 8; j++) {
    s1 += o[j];
    s2 += o[j] * o[j];
  }
#pragma unroll
  for (int of = 32; of; of >>= 1) {
    s1 += __shfl_xor(s1, of, 64);
    s2 += __shfl_xor(s2, of, 64);
  }
  float mu = s1 * (1.f / 512.f);
  float var = fmaxf(s2 * (1.f / 512.f) - mu * mu, 0.f);
  float rs = rsqrtf(var + 1e-5f);
  f32x4 gv0 = ldf4v(g + c), gv1 = ldf4v(g + c + 4);
  f32x4 ev0 = ldf4v(be + c), ev1 = ldf4v(be + c + 4);
  v8bf hv;
#pragma unroll
  for (int j = 0; j < 4; j++) {
    float y0 = (o[j] - mu) * rs * gv0[j] + ev0[j];
    float y1 = (o[4 + j] - mu) * rs * gv1[j] + ev1[j];
    y0 = y0 > 0.f ? y0 : __expf(fminf(y0, 0.f)) - 1.f;
    y1 = y1 > 0.f ? y1 : __expf(fminf(y1, 0.f)) - 1.f;
    hv[j] = (bf16)y0;
    hv[4 + j] = (bf16)y1;
  }
  __builtin_memcpy(hout + (size_t)node * D1 + c, &hv, 16);
}

__global__ __launch_bounds__(256) void agg2c_k(
    const float* __restrict__ xl, const float* __restrict__ skip,
    const float* __restrict__ alphap, const float* __restrict__ bias,
    const float* __restrict__ g, const float* __restrict__ be,
    const int* __restrict__ s_csr, const int* __restrict__ offs,
    float* __restrict__ outp) {
  int tid = threadIdx.x;
  int w = tid >> 6, l = tid & 63;
  int node = blockIdx.x * 4 + w;
  if (node >= NN) return;
  int c = 2 * l;
  int i0 = offs[node], i1 = offs[node + 1];
  i0 = max(0, min(i0, EE));
  i1 = max(i0, min(i1, EE));
  float m = -3.0e38f;
  for (int i = i0 + l; i < i1; i += 64) m = fmaxf(m, alphap[i]);
#pragma unroll
  for (int o = 32; o; o >>= 1) m = fmaxf(m, __shfl_xor(m, o, 64));
  float den = 0.f;
  f32x2 acc = {0.f, 0.f};
  int s = 0;
  float al = 0.f;
  if (i0 < i1) {
    s = __builtin_amdgcn_readfirstlane(s_csr[i0]);
    al = alphap[i0];
  }
  for (int i = i0; i < i1; i++) {
    int s_n = s;
    float al_n = al;
    if (i + 1 < i1) {
      s_n = __builtin_amdgcn_readfirstlane(s_csr[i + 1]);
      al_n = alphap[i + 1];
    }
    float pr = __expf(al - m);
    den += pr;
    f32x2 xv = ldf2v(xl + (size_t)s * DOUT + c);
    acc += (f32x2){pr, pr} * xv;
    s = s_n;
    al = al_n;
  }
  float inv = 1.f / (den + 1e-16f);
  f32x2 sk = ldf2v(skip + (size_t)node * DOUT + c);
  float o0 = acc.x * inv + bias[c] + sk.x;
  float o1 = acc.y * inv + bias[c + 1] + sk.y;
  float s1 = o0 + o1, s2 = o0 * o0 + o1 * o1;
#pragma unroll
  for (int of = 32; of; of >>= 1) {
    s1 += __shfl_xor(s1, of, 64);
    s2 += __shfl_xor(s2, of, 64);
  }
  float mu = s1 * (1.f / 128.f);
  float var = fmaxf(s2 * (1.f / 128.f) - mu * mu, 0.f);
  float rs = rsqrtf(var + 1e-5f);
  outp[(size_t)node * DOUT + c] = (o0 - mu) * rs * g[c] + be[c];
  outp[(size_t)node * DOUT + c + 1] = (o1 - mu) * rs * g[c + 1] + be[c + 1];
}

// ==== TIER-1 kernels: edge-order alpha + elist-indirect aggs ===============
__global__ __launch_bounds__(256) void alpha1_k(
    const bf16* __restrict__ xl, const bf16* __restrict__ xr,
    const float* __restrict__ eatt, const float* __restrict__ We,
    const float* __restrict__ att, const int* __restrict__ srcs,
    const int* __restrict__ dsts, float* __restrict__ alpha) {
  __shared__ bf16 ea_s[128 * 40];
  int tid = threadIdx.x;
  int w = __builtin_amdgcn_readfirstlane(tid >> 6);
  int l = tid & 63;
  int quad = l >> 4, lc = l & 15;
  int base = blockIdx.x * 128;
  for (int i = tid; i < 128 * 32; i += 256) {
    int e = i >> 5, k = i & 31;
    float v = (k < 26) ? eatt[(size_t)(base + e) * ED + k] : 0.f;
    ea_s[e * 40 + k] = (bf16)v;
  }
  int c0 = w * 128;
  v8bf bfrag[8];
  float av[8];
#pragma unroll
  for (int n = 0; n < 8; n++) {
    int col = c0 + n * 16 + lc;
    av[n] = att[col];
#pragma unroll
    for (int j = 0; j < 8; j++) {
      int k = quad * 8 + j;
      bfrag[n][j] = (k < 26) ? (bf16)We[(size_t)k * D1 + col] : (bf16)0.f;
    }
  }
  __syncthreads();
#pragma unroll 1
  for (int m = 0; m < 8; m++) {
    v8bf afrag;
    __builtin_memcpy(&afrag, &ea_s[(m * 16 + lc) * 40 + quad * 8], 16);
    f32x4 z = {0.f, 0.f, 0.f, 0.f};
    f32x4 acc[8];
#pragma unroll
    for (int n = 0; n < 8; n++)
      acc[n] = __builtin_amdgcn_mfma_f32_16x16x32_bf16(afrag, bfrag[n], z, 0, 0, 0);
    int e0 = base + m * 16 + quad * 4;
    int sA[4], dA[4];
#pragma unroll
    for (int r = 0; r < 4; r++) {
      sA[r] = srcs[e0 + r];
      dA[r] = dsts[e0 + r];
    }
    f32x4 pal = {0.f, 0.f, 0.f, 0.f};
#pragma unroll
    for (int n = 0; n < 8; n++) {
      int col = c0 + n * 16 + lc;
#pragma unroll
      for (int r = 0; r < 4; r++) {
        float mm = (float)xl[(size_t)sA[r] * D1 + col] +
                   (float)xr[(size_t)dA[r] * D1 + col] + acc[n][r];
        mm = fmaxf(mm, 0.f) + 0.2f * fminf(mm, 0.f);
        pal[r] += mm * av[n];
      }
    }
#pragma unroll
    for (int o = 1; o < 16; o <<= 1) {
      pal[0] += __shfl_xor(pal[0], o, 64);
      pal[1] += __shfl_xor(pal[1], o, 64);
      pal[2] += __shfl_xor(pal[2], o, 64);
      pal[3] += __shfl_xor(pal[3], o, 64);
    }
    if (lc == 0) {
#pragma unroll
      for (int r = 0; r < 4; r++) alpha[(size_t)(e0 + r) * 4 + w] = pal[r];
    }
  }
}

__global__ __launch_bounds__(256) void alpha2_k(
    const float* __restrict__ xl, const float* __restrict__ xr,
    const float* __restrict__ eatt, const float* __restrict__ We,
    const float* __restrict__ att, const int* __restrict__ srcs,
    const int* __restrict__ dsts, float* __restrict__ alpha) {
  __shared__ bf16 ea_s[128 * 40];
  __shared__ float pal_s[4 * 128];
  int tid = threadIdx.x;
  int w = __builtin_amdgcn_readfirstlane(tid >> 6);
  int l = tid & 63;
  int quad = l >> 4, lc = l & 15;
  int base = blockIdx.x * 128;
  for (int i = tid; i < 128 * 32; i += 256) {
    int e = i >> 5, k = i & 31;
    float v = (k < 26) ? eatt[(size_t)(base + e) * ED + k] : 0.f;
    ea_s[e * 40 + k] = (bf16)v;
  }
  int c0 = w * 32;
  v8bf bfrag[2];
  float av[2];
#pragma unroll
  for (int n = 0; n < 2; n++) {
    int col = c0 + n * 16 + lc;
    av[n] = att[col];
#pragma unroll
    for (int j = 0; j < 8; j++) {
      int k = quad * 8 + j;
      bfrag[n][j] = (k < 26) ? (bf16)We[(size_t)k * DOUT + col] : (bf16)0.f;
    }
  }
  __syncthreads();
#pragma unroll 1
  for (int m = 0; m < 8; m++) {
    v8bf afrag;
    __builtin_memcpy(&afrag, &ea_s[(m * 16 + lc) * 40 + quad * 8], 16);
    f32x4 z = {0.f, 0.f, 0.f, 0.f};
    f32x4 acc[2];
#pragma unroll
    for (int n = 0; n < 2; n++)
      acc[n] = __builtin_amdgcn_mfma_f32_16x16x32_bf16(afrag, bfrag[n], z, 0, 0, 0);
    int e0 = base + m * 16 + quad * 4;
    int sA[4], dA[4];
#pragma unroll
    for (int r = 0; r < 4; r++) {
      sA[r] = srcs[e0 + r];
      dA[r] = dsts[e0 + r];
    }
    f32x4 pal = {0.f, 0.f, 0.f, 0.f};
#pragma unroll
    for (int n = 0; n < 2; n++) {
      int col = c0 + n * 16 + lc;
#pragma unroll
      for (int r = 0; r < 4; r++) {
        float mm = xl[(size_t)sA[r] * DOUT + col] +
                   xr[(size_t)dA[r] * DOUT + col] + acc[n][r];
        mm = fmaxf(mm, 0.f) + 0.2f * fminf(mm, 0.f);
        pal[r] += mm * av[n];
      }
    }
#pragma unroll
    for (int o = 1; o < 16; o <<= 1) {
      pal[0] += __shfl_xor(pal[0], o, 64);
      pal[1] += __shfl_xor(pal[1], o, 64);
      pal[2] += __shfl_xor(pal[2], o, 64);
      pal[3] += __shfl_xor(pal[3], o, 64);
    }
    if (lc == 0) {
      int eb = m * 16 + quad * 4;
#pragma unroll
      for (int r = 0; r < 4; r++) pal_s[w * 128 + eb + r] = pal[r];
    }
  }
  __syncthreads();
  if (tid < 128) {
    float a = pal_s[tid] + pal_s[128 + tid] + pal_s[256 + tid] + pal_s[384 + tid];
    alpha[base + tid] = a;
  }
}

__global__ __launch_bounds__(256) void agg1_k(
    const bf16* __restrict__ xl, const bf16* __restrict__ skip,
    const float* __restrict__ alpha, const float* __restrict__ bias,
    const float* __restrict__ g, const float* __restrict__ be,
    const int* __restrict__ srcs, const int* __restrict__ offs,
    const int* __restrict__ elist, bf16* __restrict__ hout) {
  int tid = threadIdx.x;
  int w = tid >> 6, l = tid & 63;
  int node = blockIdx.x * 4 + w;
  if (node >= NN) return;
  int c = l * 8;
  int head = l >> 4;
  int i0 = offs[node], i1 = offs[node + 1];
  i0 = max(0, min(i0, EE));
  i1 = max(i0, min(i1, EE));
  float m = -3.0e38f;
  for (int i = i0; i < i1; i++) {
    int e = __builtin_amdgcn_readfirstlane(elist[i]);
    m = fmaxf(m, alpha[(size_t)e * 4 + head]);
  }
  float den = 0.f;
  f32x4 a0 = {0.f, 0.f, 0.f, 0.f}, a1 = {0.f, 0.f, 0.f, 0.f};
  int s = 0;
  float al = 0.f;
  if (i0 < i1) {
    int e = __builtin_amdgcn_readfirstlane(elist[i0]);
    s = __builtin_amdgcn_readfirstlane(srcs[e]);
    al = alpha[(size_t)e * 4 + head];
  }
  for (int i = i0; i < i1; i++) {
    int s_n = s;
    float al_n = al;
    if (i + 1 < i1) {
      int e = __builtin_amdgcn_readfirstlane(elist[i + 1]);
      s_n = __builtin_amdgcn_readfirstlane(srcs[e]);
      al_n = alpha[(size_t)e * 4 + head];
    }
    float pr = __expf(al - m);
    den += pr;
    v8bf xv;
    __builtin_memcpy(&xv, xl + (size_t)s * D1 + c, 16);
#pragma unroll
    for (int j = 0; j < 4; j++) {
      a0[j] += pr * (float)xv[j];
      a1[j] += pr * (float)xv[4 + j];
    }
    s = s_n;
    al = al_n;
  }
  float inv = 1.f / (den + 1e-16f);
  v8bf skv;
  __builtin_memcpy(&skv, skip + (size_t)node * D1 + c, 16);
  f32x4 bv0 = ldf4v(bias + c), bv1 = ldf4v(bias + c + 4);
  float o[8];
#pragma unroll
  for (int j = 0; j < 4; j++) {
    o[j] = a0[j] * inv + bv0[j] + (float)skv[j];
    o[4 + j] = a1[j] * inv + bv1[j] + (float)skv[4 + j];
  }
  float s1 = 0.f, s2 = 0.f;
#pragma unroll
  for (int j = 0; j < 8; j++) {
    s1 += o[j];
    s2 += o[j] * o[j];
  }
#pragma unroll
  for (int of = 32; of; of >>= 1) {
    s1 += __shfl_xor(s1, of, 64);
    s2 += __shfl_xor(s2, of, 64);
  }
  float mu = s1 * (1.f / 512.f);
  float var = fmaxf(s2 * (1.f / 512.f) - mu * mu, 0.f);
  float rs = rsqrtf(var + 1e-5f);
  f32x4 gv0 = ldf4v(g + c), gv1 = ldf4v(g + c + 4);
  f32x4 ev0 = ldf4v(be + c), ev1 = ldf4v(be + c + 4);
  v8bf hv;
#pragma unroll
  for (int j = 0; j < 4; j++) {
    float y0 = (o[j] - mu) * rs * gv0[j] + ev0[j];
    float y1 = (o[4 + j] - mu) * rs * gv1[j] + ev1[j];
    y0 = y0 > 0.f ? y0 : __expf(fminf(y0, 0.f)) - 1.f;
    y1 = y1 > 0.f ? y1 : __expf(fminf(y1, 0.f)) - 1.f;
    hv[j] = (bf16)y0;
    hv[4 + j] = (bf16)y1;
  }
  __builtin_memcpy(hout + (size_t)node * D1 + c, &hv, 16);
}

__global__ __launch_bounds__(256) void agg2_k(
    const float* __restrict__ xl, const float* __restrict__ skip,
    const float* __restrict__ alpha, const float* __restrict__ bias,
    const float* __restrict__ g, const float* __restrict__ be,
    const int* __restrict__ srcs, const int* __restrict__ offs,
    const int* __restrict__ elist, float* __restrict__ outp) {
  int tid = threadIdx.x;
  int w = tid >> 6, l = tid & 63;
  int node = blockIdx.x * 4 + w;
  if (node >= NN) return;
  int c = 2 * l;
  int i0 = offs[node], i1 = offs[node + 1];
  i0 = max(0, min(i0, EE));
  i1 = max(i0, min(i1, EE));
  float m = -3.0e38f;
  for (int i = i0; i < i1; i++) {
    int e = __builtin_amdgcn_readfirstlane(elist[i]);
    m = fmaxf(m, alpha[e]);
  }
  float den = 0.f;
  f32x2 acc = {0.f, 0.f};
  int s = 0;
  float al = 0.f;
  if (i0 < i1) {
    int e = __builtin_amdgcn_readfirstlane(elist[i0]);
    s = __builtin_amdgcn_readfirstlane(srcs[e]);
    al = alpha[e];
  }
  for (int i = i0; i < i1; i++) {
    int s_n = s;
    float al_n = al;
    if (i + 1 < i1) {
      int e = __builtin_amdgcn_readfirstlane(elist[i + 1]);
      s_n = __builtin_amdgcn_readfirstlane(srcs[e]);
      al_n = alpha[e];
    }
    float pr = __expf(al - m);
    den += pr;
    f32x2 xv = ldf2v(xl + (size_t)s * DOUT + c);
    acc += (f32x2){pr, pr} * xv;
    s = s_n;
    al = al_n;
  }
  float inv = 1.f / (den + 1e-16f);
  f32x2 sk = ldf2v(skip + (size_t)node * DOUT + c);
  float o0 = acc.x * inv + bias[c] + sk.x;
  float o1 = acc.y * inv + bias[c + 1] + sk.y;
  float s1 = o0 + o1, s2 = o0 * o0 + o1 * o1;
#pragma unroll
  for (int of = 32; of; of >>= 1) {
    s1 += __shfl_xor(s1, of, 64);
    s2 += __shfl_xor(s2, of, 64);
  }
  float mu = s1 * (1.f / 128.f);
  float var = fmaxf(s2 * (1.f / 128.f) - mu * mu, 0.f);
  float rs = rsqrtf(var + 1e-5f);
  outp[(size_t)node * DOUT + c] = (o0 - mu) * rs * g[c] + be[c];
  outp[(size_t)node * DOUT + c + 1] = (o1 - mu) * rs * g[c + 1] + be[c + 1];
}

// ---------------- fallback kernels (r12): agg w/o LN, lnelu, ln128 ---------
__global__ __launch_bounds__(256) void l1_agg(
    const bf16* __restrict__ xl, const bf16* xr,
    const float* __restrict__ eatt, const float* __restrict__ We,
    const float* __restrict__ att, const float* __restrict__ bias,
    const int* __restrict__ srcs, const int* __restrict__ offs,
    const int* __restrict__ elist, bf16* hout) {
  int node = blockIdx.x;
  int tid = threadIdx.x;
  int w = tid >> 6, l = tid & 63;
  int c = w * 128 + 2 * l;
  f32x2 we[ED];
#pragma unroll
  for (int j = 0; j < ED; j++) {
    we[j] = (f32x2){We[(size_t)j * D1 + c], We[(size_t)j * D1 + c + 1]};
  }
  f32x2 av = ldf2v(att + c);
  f32x2 rv = ldbf2v(xr + (size_t)node * D1 + c);
  float m = -3.0e38f, den = 0.f;
  f32x2 acc = {0.f, 0.f};
  int i0 = offs[node], i1 = offs[node + 1];
  i0 = max(0, min(i0, EE));
  i1 = max(i0, min(i1, EE));
  int e = 0, s = 0;
  if (i0 < i1) {
    e = __builtin_amdgcn_readfirstlane(elist[i0]);
    s = __builtin_amdgcn_readfirstlane(srcs[e]);
  }
  for (int i = i0; i < i1; i++) {
    int e_n = e, s_n = s;
    if (i + 1 < i1) {
      e_n = __builtin_amdgcn_readfirstlane(elist[i + 1]);
      s_n = __builtin_amdgcn_readfirstlane(srcs[e_n]);
    }
    f32x2 xv = ldbf2v(xl + (size_t)s * D1 + c);
    const float* ear = eatt + (size_t)e * ED;
    f32x2 et = {0.f, 0.f};
#pragma unroll
    for (int j = 0; j < ED; j += 2) {
      f32x2 t = ldf2v(ear + j);
      et += (f32x2){t.x, t.x} * we[j];
      et += (f32x2){t.y, t.y} * we[j + 1];
    }
    f32x2 mm = xv + rv + et;
    f32x2 pos = {fmaxf(mm.x, 0.f), fmaxf(mm.y, 0.f)};
    f32x2 neg = {fminf(mm.x, 0.f), fminf(mm.y, 0.f)};
    mm = pos + 0.2f * neg;
    float al = mm.x * av.x + mm.y * av.y;
#pragma unroll
    for (int o = 32; o; o >>= 1) al += __shfl_xor(al, o, 64);
    float nm = fmaxf(m, al);
    float sc = __expf(m - nm);
    float pr = __expf(al - nm);
    den = den * sc + pr;
    acc = acc * sc + (f32x2){pr, pr} * xv;
    m = nm;
    e = e_n;
    s = s_n;
  }
  float inv = 1.f / (den + 1e-16f);
  hout[(size_t)node * D1 + c] = (bf16)(acc.x * inv + bias[c]);
  hout[(size_t)node * D1 + c + 1] = (bf16)(acc.y * inv + bias[c + 1]);
}

__global__ __launch_bounds__(256) void l2_agg(
    const float* __restrict__ xl, const float* xr,
    const float* __restrict__ eatt, const float* __restrict__ We,
    const float* __restrict__ att, const float* __restrict__ bias,
    const int* __restrict__ srcs, const int* __restrict__ offs,
    const int* __restrict__ elist, float* hout) {
  int tid = threadIdx.x;
  int w = tid >> 6, l = tid & 63;
  int node = blockIdx.x * 4 + w;
  if (node >= NN) return;
  int c = 2 * l;
  f32x2 we[ED];
#pragma unroll
  for (int j = 0; j < ED; j++) {
    we[j] = (f32x2){We[(size_t)j * DOUT + c], We[(size_t)j * DOUT + c + 1]};
  }
  f32x2 av = ldf2v(att + c);
  f32x2 rv = ldf2v(xr + (size_t)node * DOUT + c);
  float m = -3.0e38f, den = 0.f;
  f32x2 acc = {0.f, 0.f};
  int i0 = offs[node], i1 = offs[node + 1];
  i0 = max(0, min(i0, EE));
  i1 = max(i0, min(i1, EE));
  int e = 0, s = 0;
  if (i0 < i1) {
    e = __builtin_amdgcn_readfirstlane(elist[i0]);
    s = __builtin_amdgcn_readfirstlane(srcs[e]);
  }
  for (int i = i0; i < i1; i++) {
    int e_n = e, s_n = s;
    if (i + 1 < i1) {
      e_n = __builtin_amdgcn_readfirstlane(elist[i + 1]);
      s_n = __builtin_amdgcn_readfirstlane(srcs[e_n]);
    }
    f32x2 xv = ldf2v(xl + (size_t)s * DOUT + c);
    const float* ear = eatt + (size_t)e * ED;
    f32x2 et = {0.f, 0.f};
#pragma unroll
    for (int j = 0; j < ED; j += 2) {
      f32x2 t = ldf2v(ear + j);
      et += (f32x2){t.x, t.x} * we[j];
      et += (f32x2){t.y, t.y} * we[j + 1];
    }
    f32x2 mm = xv + rv + et;
    f32x2 pos = {fmaxf(mm.x, 0.f), fmaxf(mm.y, 0.f)};
    f32x2 neg = {fminf(mm.x, 0.f), fminf(mm.y, 0.f)};
    mm = pos + 0.2f * neg;
    float al = mm.x * av.x + mm.y * av.y;
#pragma unroll
    for (int o = 32; o; o >>= 1) al += __shfl_xor(al, o, 64);
    float nm = fmaxf(m, al);
    float sc = __expf(m - nm);
    float pr = __expf(al - nm);
    den = den * sc + pr;
    acc = acc * sc + (f32x2){pr, pr} * xv;
    m = nm;
    e = e_n;
    s = s_n;
  }
  float inv = 1.f / (den + 1e-16f);
  hout[(size_t)node * DOUT + c] = acc.x * inv + bias[c];
  hout[(size_t)node * DOUT + c + 1] = acc.y * inv + bias[c + 1];
}

__global__ __launch_bounds__(256) void lnelu_k(bf16* buf,
                                               const float* __restrict__ g,
                                               const float* __restrict__ be) {
  int node = blockIdx.x, tid = threadIdx.x;
  int w = tid >> 6, l = tid & 63;
  int c = tid * 2;
  f32x2 o = ldbf2v(buf + (size_t)node * D1 + c);
  float s1 = o.x + o.y, s2 = o.x * o.x + o.y * o.y;
#pragma unroll
  for (int of = 32; of; of >>= 1) {
    s1 += __shfl_xor(s1, of, 64);
    s2 += __shfl_xor(s2, of, 64);
  }
  __shared__ float r1[4], r2[4];
  if (l == 0) { r1[w] = s1; r2[w] = s2; }
  __syncthreads();
  float S1 = r1[0] + r1[1] + r1[2] + r1[3];
  float S2 = r2[0] + r2[1] + r2[2] + r2[3];
  float mu = S1 * (1.f / 512.f);
  float var = fmaxf(S2 * (1.f / 512.f) - mu * mu, 0.f);
  float rs = rsqrtf(var + 1e-5f);
  float y0 = (o.x - mu) * rs * g[c] + be[c];
  float y1 = (o.y - mu) * rs * g[c + 1] + be[c + 1];
  y0 = y0 > 0.f ? y0 : __expf(fminf(y0, 0.f)) - 1.f;
  y1 = y1 > 0.f ? y1 : __expf(fminf(y1, 0.f)) - 1.f;
  buf[(size_t)node * D1 + c] = (bf16)y0;
  buf[(size_t)node * D1 + c + 1] = (bf16)y1;
}

__global__ __launch_bounds__(256) void ln128_k(const float* __restrict__ buf,
                                               const float* __restrict__ g,
                                               const float* __restrict__ be,
                                               float* __restrict__ outp) {
  int tid = threadIdx.x;
  int w = tid >> 6, l = tid & 63;
  int node = blockIdx.x * 4 + w;
  if (node >= NN) return;
  int c = 2 * l;
  f32x2 o = ldf2v(buf + (size_t)node * DOUT + c);
  float s1 = o.x + o.y, s2 = o.x * o.x + o.y * o.y;
#pragma unroll
  for (int of = 32; of; of >>= 1) {
    s1 += __shfl_xor(s1, of, 64);
    s2 += __shfl_xor(s2, of, 64);
  }
  float mu = s1 * (1.f / 128.f);
  float var = fmaxf(s2 * (1.f / 128.f) - mu * mu, 0.f);
  float rs = rsqrtf(var + 1e-5f);
  outp[(size_t)node * DOUT + c] = (o.x - mu) * rs * g[c] + be[c];
  outp[(size_t)node * DOUT + c + 1] = (o.y - mu) * rs * g[c + 1] + be[c + 1];
}

extern "C" void kernel_launch(void* const* d_in, const int* in_sizes, int n_in,
                              void* d_out, int out_size, void* d_ws, size_t ws_size,
                              hipStream_t stream) {
  const float* x = (const float*)d_in[0];
  const void* ei = d_in[1];
  const float* eattr = (const float*)d_in[2];
  const float* W1l = (const float*)d_in[3];
  const float* b1l = (const float*)d_in[4];
  const float* W1r = (const float*)d_in[5];
  const float* b1r = (const float*)d_in[6];
  const float* We1 = (const float*)d_in[7];
  const float* att1 = (const float*)d_in[8];
  const float* bias1 = (const float*)d_in[9];
  const float* Wsk1 = (const float*)d_in[10];
  const float* bsk1 = (const float*)d_in[11];
  const float* g1 = (const float*)d_in[12];
  const float* be1 = (const float*)d_in[13];
  const float* W2l = (const float*)d_in[14];
  const float* b2l = (const float*)d_in[15];
  const float* W2r = (const float*)d_in[16];
  const float* b2r = (const float*)d_in[17];
  const float* We2 = (const float*)d_in[18];
  const float* att2 = (const float*)d_in[19];
  const float* bias2 = (const float*)d_in[20];
  const float* Wsk2 = (const float*)d_in[21];
  const float* bsk2 = (const float*)d_in[22];
  const float* g2 = (const float*)d_in[23];
  const float* be2 = (const float*)d_in[24];

  // workspace carve (256B aligned)
  char* p = (char*)d_ws;
  size_t off = 0;
  auto carve = [&](size_t bytes) {
    void* r = p + off;
    off = (off + bytes + 255) & ~(size_t)255;
    return r;
  };
  int* flag = (int*)carve(sizeof(int));
  int* srcD = (int*)carve(EE * sizeof(int));
  int* dstD = (int*)carve(EE * sizeof(int));
  int* deg = (int*)carve(NN * sizeof(int));
  int* offs = (int*)carve((NN + 1) * sizeof(int));
  int* cursor = (int*)carve(NN * sizeof(int));
  int* elist = (int*)carve(EE * sizeof(int));
  bf16* bufA = (bf16*)carve((size_t)NN * D1 * 2);  // xl1; then f32 x2l/x2r
  bf16* bufB = (bf16*)carve((size_t)NN * D1 * 2);  // xr1 -> h -> alpha2 scratch
  size_t base_need = off;
  bf16* bufC = (bf16*)carve((size_t)NN * D1 * 2);  // skip1 bf16 / skip2 f32
  bool fused = (off <= ws_size);
  // tier-2 extras: CSR-gathered edge data
  bf16* eacsr = (bf16*)carve((size_t)EE * 32 * 2);  // [E][32] bf16, K-pad 0
  int* s_csr = (int*)carve(EE * sizeof(int));
  int* d_csr = (int*)carve(EE * sizeof(int));
  bool fused2 = (off <= ws_size);
  // tier-3: x pre-packed to bf16 (layer-1 GEMM A fast path)
  bf16* xbf = (bf16*)carve((size_t)NN * FIN * 2);
  bool fused3 = (off <= ws_size);

  float* q0 = (float*)bufA;              // x2l (f32)
  float* q1 = q0 + (size_t)NN * DOUT;    // x2r (f32)
  float* sk2 = (float*)bufC;             // skip2 (f32, fused path)
  float* alph1 = (float*)d_out;          // [E,4] logits
  float* alph2 = (float*)bufB;           // [E] logits
  // d_out tail (agg2 rewrites all of d_out at the very end):
  bf16* W1p = (bf16*)((char*)d_out + 5120000);   // 3 x 512x256 bf16
  bf16* W2p = W1p + (size_t)3 * D1 * FIN;        // 3 x 128x512 bf16
  bf16* Wep1 = W2p + (size_t)3 * DOUT * D1;      // 16384 bf16 (32 KB)
  bf16* Wep2 = Wep1 + 16384;                     // 4096 bf16 (8 KB)

  // ---- preprocessing ----
  if (fused2) {
    zero2_k<<<(NN + 255) / 256, 256, 0, stream>>>(deg, flag);
    detflag_k<<<(EE + 255) / 256, 256, 0, stream>>>((const int*)ei, flag);
    conv_hist_k<<<(EE + 255) / 256, 256, 0, stream>>>(ei, flag, srcD, dstD, deg);
    scan_k<<<1, 1024, 0, stream>>>(deg, offs, cursor, NN);
    scatter_eg_k<<<(EE + 255) / 256, 256, 0, stream>>>(
        eattr, srcD, dstD, cursor, elist, eacsr, s_csr, d_csr);
  } else {
    zero_k<<<1, 256, 0, stream>>>(flag, 1);
    detflag_k<<<(EE + 255) / 256, 256, 0, stream>>>((const int*)ei, flag);
    conv_k<<<(EE + 255) / 256, 256, 0, stream>>>(ei, flag, srcD, dstD);
    zero_k<<<(NN + 255) / 256, 256, 0, stream>>>(deg, NN);
    hist_k<<<(EE + 255) / 256, 256, 0, stream>>>(dstD, deg, EE);
    scan_k<<<1, 1024, 0, stream>>>(deg, offs, cursor, NN);
    scatter_k<<<(EE + 255) / 256, 256, 0, stream>>>(dstD, cursor, elist, EE);
  }

  if (fused) {
    // one launch for all weight/input packing (xpack blocks only if fused3)
    packall_k<<<fused3 ? 3156 : 656, 256, 0, stream>>>(
        W1l, W1r, Wsk1, W2l, W2r, Wsk2, We1, We2, x, W1p, W2p, Wep1, Wep2, xbf);
    // layer-1 GEMM
    if (fused3) {
      gemm3p_t<bf16, bf16><<<dim3(D1 / 64, (NN + 63) / 64), 256, 0, stream>>>(
          xbf, W1p, b1l, b1r, bsk1, bufA, bufB, bufC, D1, FIN, NN);
    } else {
      gemm3p_t<float, bf16><<<dim3(D1 / 64, (NN + 63) / 64), 256, 0, stream>>>(
          x, W1p, b1l, b1r, bsk1, bufA, bufB, bufC, D1, FIN, NN);
    }
    if (fused2) {
      alpha1c_k<<<EE / 128, 256, 0, stream>>>(bufA, bufB, eacsr, Wep1, att1,
                                              s_csr, d_csr, alph1);
      agg1c_k<<<(NN + 3) / 4, 256, 0, stream>>>(bufA, bufC, alph1, bias1, g1,
                                                be1, s_csr, offs, bufB);
      gemm3p_t<bf16, float><<<dim3(DOUT / 64, (NN + 63) / 64), 256, 0, stream>>>(
          bufB, W2p, b2l, b2r, bsk2, q0, q1, sk2, DOUT, D1, NN);
      alpha2c_k<<<EE / 128, 256, 0, stream>>>(q0, q1, eacsr, Wep2, att2,
                                              s_csr, d_csr, alph2);
      agg2c_k<<<(NN + 3) / 4, 256, 0, stream>>>(q0, sk2, alph2, bias2, g2, be2,
                                                s_csr, offs, (float*)d_out);
    } else {
      alpha1_k<<<EE / 128, 256, 0, stream>>>(bufA, bufB, eattr, We1, att1,
                                             srcD, dstD, alph1);
      agg1_k<<<(NN + 3) / 4, 256, 0, stream>>>(bufA, bufC, alph1, bias1, g1,
                                               be1, srcD, offs, elist, bufB);
      gemm3p_t<bf16, float><<<dim3(DOUT / 64, (NN + 63) / 64), 256, 0, stream>>>(
          bufB, W2p, b2l, b2r, bsk2, q0, q1, sk2, DOUT, D1, NN);
      alpha2_k<<<EE / 128, 256, 0, stream>>>(q0, q1, eattr, We2, att2,
                                             srcD, dstD, alph2);
      agg2_k<<<(NN + 3) / 4, 256, 0, stream>>>(q0, sk2, alph2, bias2, g2, be2,
                                               srcD, offs, elist, (float*)d_out);
    }
  } else {
    // r12 fallback path (fits in base_need bytes)
    (void)base_need;
    gemm2_t<float, bf16><<<dim3(D1 / 64, NN / 16), 256, 0, stream>>>(
        x, W1l, W1r, b1l, b1r, bufA, bufB, D1, FIN);
    l1_agg<<<NN, 256, 0, stream>>>(bufA, bufB, eattr, We1, att1, bias1,
                                   srcD, offs, elist, bufB);
    gemm_t<float, bf16, true><<<dim3(D1 / 64, NN / 16), 256, 0, stream>>>(
        x, Wsk1, bsk1, bufB, D1, FIN);
    lnelu_k<<<NN, 256, 0, stream>>>(bufB, g1, be1);
    gemm2_t<bf16, float><<<dim3(DOUT / 64, NN / 16), 256, 0, stream>>>(
        bufB, W2l, W2r, b2l, b2r, q0, q1, DOUT, D1);
    l2_agg<<<(NN + 3) / 4, 256, 0, stream>>>(q0, q1, eattr, We2, att2, bias2,
                                             srcD, offs, elist, q1);
    gemm_t<bf16, float, true><<<dim3(DOUT / 64, NN / 16), 256, 0, stream>>>(
        bufB, Wsk2, bsk2, q1, DOUT, D1);
    ln128_k<<<(NN + 3) / 4, 256, 0, stream>>>(q1, g2, be2, (float*)d_out);
  }

  (void)in_sizes; (void)n_in; (void)out_size;
}